// Round 10
// baseline (170.890 us; speedup 1.0000x reference)
//
#include <hip/hip_runtime.h>
#include <math.h>

#define AS3 __attribute__((address_space(3)))
#define AS1 __attribute__((address_space(1)))

typedef unsigned short u16;
typedef unsigned int u32;
typedef __bf16 bf16_t;
typedef bf16_t bf16x8 __attribute__((ext_vector_type(8)));
typedef float f32x4 __attribute__((ext_vector_type(4)));
typedef float f32x16 __attribute__((ext_vector_type(16)));
typedef unsigned short u16x8 __attribute__((ext_vector_type(8)));
typedef unsigned int u32x4 __attribute__((ext_vector_type(4)));

#define NH 16
#define DK 64
#define DC 256
#define DM 1024
#define BB 2
#define SS 2048
#define TT (BB*SS)

__device__ __forceinline__ u16 f2bf(float f) {
    unsigned u = __builtin_bit_cast(unsigned, f);
    unsigned r = (u + 0x7FFFu + ((u >> 16) & 1u)) >> 16;
    return (u16)r;
}

__device__ __forceinline__ u32 cvtpk_bf16(float a, float b) {
    u32 d;
    asm("v_cvt_pk_bf16_f32 %0, %1, %2" : "=v"(d) : "v"(a), "v"(b));
    return d;
}

__device__ __forceinline__ bf16x8 lds_frag(const char* p) {
    return __builtin_bit_cast(bf16x8, *reinterpret_cast<const u16x8*>(p));
}

__device__ __forceinline__ bf16x8 gload(const u16* p) {
    return __builtin_bit_cast(bf16x8, *reinterpret_cast<const u16x8*>(p));
}

// ---------------- fused prep: x->bf16 (z=6) + 6 weight transposes (z=0..5) ----------------
__global__ __launch_bounds__(256) void prep(const float* __restrict__ x, u16* __restrict__ xb,
                                            const float* w0, const float* w1, const float* w2,
                                            const float* w3, const float* w4, const float* w5,
                                            u16* d0, u16* d1, u16* d2, u16* d3, u16* d4, u16* d5) {
    __shared__ float t[32][33];
    const int z = blockIdx.z;
    if (z == 6) {
        int blk = blockIdx.y * 32 + blockIdx.x;
        int i = (blk * 256 + threadIdx.x) * 16;
        float4 v0 = *reinterpret_cast<const float4*>(x + i);
        float4 v1 = *reinterpret_cast<const float4*>(x + i + 4);
        float4 v2 = *reinterpret_cast<const float4*>(x + i + 8);
        float4 v3 = *reinterpret_cast<const float4*>(x + i + 12);
        u16x8 o0, o1;
        o0[0] = f2bf(v0.x); o0[1] = f2bf(v0.y); o0[2] = f2bf(v0.z); o0[3] = f2bf(v0.w);
        o0[4] = f2bf(v1.x); o0[5] = f2bf(v1.y); o0[6] = f2bf(v1.z); o0[7] = f2bf(v1.w);
        o1[0] = f2bf(v2.x); o1[1] = f2bf(v2.y); o1[2] = f2bf(v2.z); o1[3] = f2bf(v2.w);
        o1[4] = f2bf(v3.x); o1[5] = f2bf(v3.y); o1[6] = f2bf(v3.z); o1[7] = f2bf(v3.w);
        *reinterpret_cast<u16x8*>(xb + i) = o0;
        *reinterpret_cast<u16x8*>(xb + i + 8) = o1;
        return;
    }
    const float* src; u16* dst; int R, C, opitch;
    switch (z) {
        case 0:  src = w0; dst = d0; R = 1024; C = 256;  opitch = 1024; break;
        case 1:  src = w1; dst = d1; R = 1024; C = 256;  opitch = 1024; break;
        case 2:  src = w2; dst = d2; R = 256;  C = 1024; opitch = 256;  break;
        case 3:  src = w3; dst = d3; R = 256;  C = 1024; opitch = 256;  break;
        case 4:  src = w4; dst = d4; R = 256;  C = 1024; opitch = 256;  break;
        default: src = w5; dst = d5; R = 1024; C = 1024; opitch = 1024; break;
    }
    int c0 = blockIdx.x * 32, r0 = blockIdx.y * 32;
    if (c0 >= C || r0 >= R) return;
    int tx = threadIdx.x & 31, ty = threadIdx.x >> 5;
    #pragma unroll
    for (int p = 0; p < 4; ++p)
        t[ty + 8 * p][tx] = src[(r0 + ty + 8 * p) * C + c0 + tx];
    __syncthreads();
    #pragma unroll
    for (int p = 0; p < 4; ++p)
        dst[(c0 + ty + 8 * p) * opitch + r0 + tx] = f2bf(t[tx][ty + 8 * p]);
}

// ---------------- MFMA GEMM body: C[128 x BN] tile at (bm, bn) ----------------
template <int BN, bool OUT_BF16>
__device__ __forceinline__ void gemm_body(const u16* __restrict__ A, int lda,
                                          const u16* __restrict__ Bt, int ldb,
                                          void* __restrict__ C, int ldc, int K,
                                          int bm, int bn, u16* As, u16* Bs) {
    constexpr int NF = BN / 32;
    constexpr int BI = BN / 64;
    const int tid = threadIdx.x;
    const int lane = tid & 63;
    const int w = tid >> 6;
    const int wr = w >> 1, wc = w & 1;
    const int l15 = lane & 15, l4 = lane >> 4;

    f32x4 acc[4][NF] = {};

    for (int k0 = 0; k0 < K; k0 += 32) {
        #pragma unroll
        for (int i = 0; i < 2; ++i) {
            int db = i * 4096 + tid * 16;
            int row = db >> 6;
            int kc = (db & 63) >> 1;
            __builtin_amdgcn_global_load_lds(
                (const AS1 void*)(A + (bm + row) * lda + k0 + kc),
                (AS3 void*)((AS3 char*)(AS3 void*)As + i * 4096 + w * 1024), 16, 0, 0);
        }
        #pragma unroll
        for (int i = 0; i < BI; ++i) {
            int db = i * 4096 + tid * 16;
            int row = db >> 6;
            int kc = (db & 63) >> 1;
            __builtin_amdgcn_global_load_lds(
                (const AS1 void*)(Bt + (bn + row) * ldb + k0 + kc),
                (AS3 void*)((AS3 char*)(AS3 void*)Bs + i * 4096 + w * 1024), 16, 0, 0);
        }
        __syncthreads();
        bf16x8 a[4], b[NF];
        #pragma unroll
        for (int m = 0; m < 4; ++m)
            a[m] = __builtin_bit_cast(bf16x8,
                *reinterpret_cast<const u16x8*>(&As[(wr * 64 + m * 16 + l15) * 32 + l4 * 8]));
        #pragma unroll
        for (int n = 0; n < NF; ++n)
            b[n] = __builtin_bit_cast(bf16x8,
                *reinterpret_cast<const u16x8*>(&Bs[(wc * (BN / 2) + n * 16 + l15) * 32 + l4 * 8]));
        #pragma unroll
        for (int m = 0; m < 4; ++m)
            #pragma unroll
            for (int n = 0; n < NF; ++n)
                acc[m][n] = __builtin_amdgcn_mfma_f32_16x16x32_bf16(a[m], b[n], acc[m][n], 0, 0, 0);
        __syncthreads();
    }
    #pragma unroll
    for (int m = 0; m < 4; ++m) {
        int row = bm + wr * 64 + m * 16 + l4 * 4;
        #pragma unroll
        for (int j = 0; j < 4; ++j) {
            #pragma unroll
            for (int n = 0; n < NF; ++n) {
                int col = bn + wc * (BN / 2) + n * 16 + l15;
                if (OUT_BF16)
                    ((u16*)C)[(row + j) * ldc + col] = f2bf(acc[m][n][j]);
                else
                    ((float*)C)[(row + j) * ldc + col] = acc[m][n][j];
            }
        }
    }
}

template <int BN, bool OUT_BF16>
__global__ __launch_bounds__(256) void gemmT(const u16* __restrict__ A, int lda,
                                             const u16* __restrict__ Bt, int ldb,
                                             void* __restrict__ C, int ldc, int K) {
    __shared__ u16 As[128 * 32];
    __shared__ u16 Bs[BN * 32];
    gemm_body<BN, OUT_BF16>(A, lda, Bt, ldb, C, ldc, K, blockIdx.y * 128, blockIdx.x * BN, As, Bs);
}

// fused Q + KV up-projection: bx<8 -> Q tile, else KV tile. K=256 both.
__global__ __launch_bounds__(256) void gemm_qkv(const u16* __restrict__ c_qkv,
                                                const u16* __restrict__ Wuq_t,
                                                const u16* __restrict__ Wukv_t,
                                                u16* __restrict__ Qb, u16* __restrict__ KVb) {
    __shared__ u16 As[128 * 32];
    __shared__ u16 Bs[128 * 32];
    const int bx = blockIdx.x;
    if (bx < 8) {
        gemm_body<128, true>(c_qkv, 512, Wuq_t, 256, Qb, 1024, 256,
                             blockIdx.y * 128, bx * 128, As, Bs);
    } else {
        gemm_body<128, true>(c_qkv + 256, 512, Wukv_t, 256, KVb, 2048, 256,
                             blockIdx.y * 128, (bx - 8) * 128, As, Bs);
    }
}

// ---------------- V transpose: Vt[b*1024 + c][s] = KVb[b*2048+s][1024+c] ----------------
__global__ __launch_bounds__(256) void vt_kernel(const u16* __restrict__ KVb, u16* __restrict__ Vt) {
    __shared__ u16 t[32][34];
    const int bb = blockIdx.z;
    const u16* in = KVb + (size_t)bb * SS * 2048 + 1024;
    u16* out = Vt + (size_t)bb * 1024 * 2048;
    int c0 = blockIdx.x * 32, r0 = blockIdx.y * 32;
    int tx = threadIdx.x & 31, ty = threadIdx.x >> 5;
    #pragma unroll
    for (int p = 0; p < 4; ++p)
        t[ty + 8 * p][tx] = in[(size_t)(r0 + ty + 8 * p) * 2048 + c0 + tx];
    __syncthreads();
    #pragma unroll
    for (int p = 0; p < 4; ++p)
        out[(size_t)(c0 + ty + 8 * p) * 2048 + r0 + tx] = t[tx][ty + 8 * p];
}

// ---------------- MFMA causal flash attention v9 ----------------
// Block = (bq 64 q-rows, bh), 4 waves. Pair-parity: waves {0,1} even tiles,
// {2,3} odd tiles. K LDS-staged (double-buffered, 32 KB); V direct global->reg.
// Uniform CU-load bq mapping (4 resident blocks/CU sum to equal work).
__global__ __launch_bounds__(256, 4) void attn_mfma7(const u16* __restrict__ Qb,
                                                     const u16* __restrict__ KVb,
                                                     const u16* __restrict__ VtG,
                                                     u16* __restrict__ O) {
    __shared__ char lds[34304];   // 4 x 8KB K slots; aliased by combine (33280+1024)
    const int bid = blockIdx.x;
    const int g = bid >> 8, u = (bid >> 5) & 7;
    const int bq = (g == 0) ? (31 - u) : (g == 1) ? (16 + u) : (g == 2) ? (15 - u) : u;
    const int bh = bid & 31;
    const int b = bh >> 4, head = bh & 15;
    const int tid = threadIdx.x;
    const int w = tid >> 6;
    const int lane = tid & 63;
    const int l31 = lane & 31, hi = lane >> 5;
    const int r7 = l31 & 7;
    const int pair = w >> 1, sub = w & 1;
    const int q0 = bq * 64;
    const int qg = q0 + sub * 32 + l31;
    const int rounds = (bq >> 1) + 1;
    const float c2 = 0.125f * 1.44269504088896340736f;  // scale * log2(e)
    const float THRraw = 44.3614195558f;                // 8 / c2

    // Q fragments (B-operand): Q[q][16kc + 8hi + 0..7]
    bf16x8 qf[4];
    {
        const u16* qp = Qb + (size_t)(b * SS + qg) * 1024 + head * 64 + hi * 8;
        #pragma unroll
        for (int kc = 0; kc < 4; ++kc)
            qf[kc] = __builtin_bit_cast(bf16x8, *reinterpret_cast<const u16x8*>(qp + kc * 16));
    }
    const u16* vbase = VtG + (size_t)(bh * 64 + l31) * 2048 + hi * 8;

    f32x16 acc0 = {}, acc1 = {};   // O^T partial: d rows (0..31 / 32..63), col = q
    float mrow = -3.0e38f, lrow = 0.f;

#define STAGE2(cur_, r_) do { \
    _Pragma("unroll") \
    for (int p_ = 0; p_ < 2; ++p_) { \
        int kt_ = 2 * (r_) + p_; \
        if (kt_ <= bq) { \
            int k0_ = kt_ * 64; \
            char* base_ = lds + (((cur_) << 1) | p_) * 8192; \
            _Pragma("unroll") \
            for (int c_ = 0; c_ < 2; ++c_) { \
                int i_ = tid + 256 * c_; int row_ = i_ >> 3; int sc_ = (i_ & 7) ^ (row_ & 7); \
                __builtin_amdgcn_global_load_lds( \
                    (const AS1 void*)(KVb + (size_t)(b * SS + k0_ + row_) * 2048 + head * 64 + sc_ * 8), \
                    (AS3 void*)((AS3 char*)(AS3 void*)base_ + c_ * 4096 + w * 1024), 16, 0, 0); \
            } \
        } \
    } } while (0)

    int cur = 0;
    STAGE2(0, 0);
    __syncthreads();

    for (int r = 0; r < rounds; ++r) {
        const int kt = 2 * r + pair;
        const bool active = (kt <= bq);
        // V loads FIRST (so PV's vmcnt wait doesn't drain the prefetch below)
        bf16x8 vfa[4], vfb[4];
        if (active) {
            const u16* vr = vbase + kt * 64;
            #pragma unroll
            for (int ks = 0; ks < 4; ++ks) {
                vfa[ks] = gload(vr + ks * 16);
                vfb[ks] = gload(vr + 32 * 2048 + ks * 16);
            }
        }
        if (r + 1 < rounds) STAGE2(cur ^ 1, r + 1);
        if (active) {
            const char* Kb_ = lds + ((cur << 1) | pair) * 8192;
            const int k0 = kt * 64;
            // S^T = K @ Q^T
            f32x16 s0 = {}, s1 = {};
            __builtin_amdgcn_s_setprio(1);
            #pragma unroll
            for (int kc = 0; kc < 4; ++kc) {
                bf16x8 kf0 = lds_frag(Kb_ + (l31) * 128 + ((2 * kc + hi) ^ r7) * 16);
                bf16x8 kf1 = lds_frag(Kb_ + (32 + l31) * 128 + ((2 * kc + hi) ^ r7) * 16);
                s0 = __builtin_amdgcn_mfma_f32_32x32x16_bf16(kf0, qf[kc], s0, 0, 0, 0);
                s1 = __builtin_amdgcn_mfma_f32_32x32x16_bf16(kf1, qf[kc], s1, 0, 0, 0);
            }
            __builtin_amdgcn_s_setprio(0);
            if (kt == bq) {   // diagonal tile: causal mask
                const int lim = qg - k0 - hi * 4;
                #pragma unroll
                for (int r2 = 0; r2 < 16; ++r2) {
                    const int ko = (r2 & 3) + 8 * (r2 >> 2);
                    s0[r2] = (ko > lim) ? -3.0e38f : s0[r2];
                    s1[r2] = (ko + 32 > lim) ? -3.0e38f : s1[r2];
                }
            }
            // tree max + cross-half exchange
            float a8[8];
            #pragma unroll
            for (int i = 0; i < 8; ++i)
                a8[i] = fmaxf(fmaxf(s0[2 * i], s0[2 * i + 1]), fmaxf(s1[2 * i], s1[2 * i + 1]));
            float tm = fmaxf(fmaxf(fmaxf(a8[0], a8[1]), fmaxf(a8[2], a8[3])),
                             fmaxf(fmaxf(a8[4], a8[5]), fmaxf(a8[6], a8[7])));
            tm = fmaxf(tm, __shfl_xor(tm, 32));
            // defer-max
            bool nofix = __all(tm <= mrow + THRraw);
            float scale = 1.f;
            if (!nofix) {
                float mnew = fmaxf(mrow, tm);
                scale = exp2f((mrow - mnew) * c2);
                mrow = mnew;
            }
            float mc = mrow * c2;
            #pragma unroll
            for (int r2 = 0; r2 < 16; ++r2) {
                s0[r2] = exp2f(__builtin_fmaf(s0[r2], c2, -mc));
                s1[r2] = exp2f(__builtin_fmaf(s1[r2], c2, -mc));
            }
            float c8[8];
            #pragma unroll
            for (int i = 0; i < 8; ++i)
                c8[i] = (s0[2 * i] + s0[2 * i + 1]) + (s1[2 * i] + s1[2 * i + 1]);
            float rsum = ((c8[0] + c8[1]) + (c8[2] + c8[3])) + ((c8[4] + c8[5]) + (c8[6] + c8[7]));
            rsum += __shfl_xor(rsum, 32);
            if (nofix) {
                lrow += rsum;
            } else {
                lrow = lrow * scale + rsum;
                #pragma unroll
                for (int r2 = 0; r2 < 16; ++r2) { acc0[r2] *= scale; acc1[r2] *= scale; }
            }
            // pack P to bf16 pairs
            u32 cg0[4][2], cg1[4][2];
            #pragma unroll
            for (int gg = 0; gg < 4; ++gg) {
                #pragma unroll
                for (int w2 = 0; w2 < 2; ++w2) {
                    cg0[gg][w2] = cvtpk_bf16(s0[4 * gg + 2 * w2], s0[4 * gg + 2 * w2 + 1]);
                    cg1[gg][w2] = cvtpk_bf16(s1[4 * gg + 2 * w2], s1[4 * gg + 2 * w2 + 1]);
                }
            }
            // assemble P frags via shfl_xor(32): pa[ks] = P[q][16ks + 8hi + 0..7]
            bf16x8 pa[4];
            #pragma unroll
            for (int ks = 0; ks < 4; ++ks) {
                const int g0 = (2 * ks) & 3, g1 = g0 + 1;
                u32 a0, a1, b0, b1;
                if (ks < 2) { a0 = cg0[g0][0]; a1 = cg0[g0][1]; b0 = cg0[g1][0]; b1 = cg0[g1][1]; }
                else        { a0 = cg1[g0][0]; a1 = cg1[g0][1]; b0 = cg1[g1][0]; b1 = cg1[g1][1]; }
                u32 pa0 = (u32)__shfl_xor((int)a0, 32);
                u32 pa1 = (u32)__shfl_xor((int)a1, 32);
                u32 pb0 = (u32)__shfl_xor((int)b0, 32);
                u32 pb1 = (u32)__shfl_xor((int)b1, 32);
                u32x4 f;
                f.x = hi ? pb0 : a0;
                f.y = hi ? pb1 : a1;
                f.z = hi ? b0 : pa0;
                f.w = hi ? b1 : pa1;
                pa[ks] = __builtin_bit_cast(bf16x8, f);
            }
            // O^T += V^T @ P^T
            __builtin_amdgcn_s_setprio(1);
            #pragma unroll
            for (int ks = 0; ks < 4; ++ks) {
                acc0 = __builtin_amdgcn_mfma_f32_32x32x16_bf16(vfa[ks], pa[ks], acc0, 0, 0, 0);
                acc1 = __builtin_amdgcn_mfma_f32_32x32x16_bf16(vfb[ks], pa[ks], acc1, 0, 0, 0);
            }
            __builtin_amdgcn_s_setprio(0);
        }
        __syncthreads();
        cur ^= 1;
    }
#undef STAGE2

    // write partials to LDS (aliases staging region; all compute done)
    float* part = (float*)lds;                    // [4][32][65]
    float* mls  = (float*)(lds + 33280);          // [4][2][32]
    #pragma unroll
    for (int r2 = 0; r2 < 16; ++r2) {
        const int d = (r2 & 3) + 8 * (r2 >> 2) + 4 * hi;
        part[(w * 32 + l31) * 65 + d] = acc0[r2];
        part[(w * 32 + l31) * 65 + d + 32] = acc1[r2];
    }
    if (hi == 0) {
        mls[(w * 2 + 0) * 32 + l31] = mrow;
        mls[(w * 2 + 1) * 32 + l31] = lrow;
    }
    __syncthreads();

    // combine 2 partials: thread -> q = tid>>2 (0..63), d-seg = (tid&3)*16
    {
        const int q = tid >> 2, ds0 = (tid & 3) * 16;
        const int s_ = q >> 5, qq = q & 31;
        const int wa_ = s_, wb_ = 2 + s_;
        float ma = mls[(wa_ * 2 + 0) * 32 + qq], la = mls[(wa_ * 2 + 1) * 32 + qq];
        float mb = mls[(wb_ * 2 + 0) * 32 + qq], lb = mls[(wb_ * 2 + 1) * 32 + qq];
        float mt = fmaxf(ma, mb);
        float wa = exp2f((ma - mt) * c2);
        float wb = exp2f((mb - mt) * c2);
        float lt = la * wa + lb * wb;
        float inv = 1.0f / lt;
        u16x8 ov0, ov1;
        #pragma unroll
        for (int i = 0; i < 8; ++i) {
            float v0 = part[(wa_ * 32 + qq) * 65 + ds0 + i] * wa +
                       part[(wb_ * 32 + qq) * 65 + ds0 + i] * wb;
            float v1 = part[(wa_ * 32 + qq) * 65 + ds0 + 8 + i] * wa +
                       part[(wb_ * 32 + qq) * 65 + ds0 + 8 + i] * wb;
            ov0[i] = f2bf(v0 * inv);
            ov1[i] = f2bf(v1 * inv);
        }
        u16* op = O + (size_t)(b * SS + q0 + q) * 1024 + head * 64 + ds0;
        *reinterpret_cast<u16x8*>(op) = ov0;
        *reinterpret_cast<u16x8*>(op + 8) = ov1;
    }
}

// ---------------- launch ----------------

extern "C" void kernel_launch(void* const* d_in, const int* in_sizes, int n_in,
                              void* d_out, int out_size, void* d_ws, size_t ws_size,
                              hipStream_t stream) {
    const float* x     = (const float*)d_in[0];
    const float* W_dq  = (const float*)d_in[1];
    const float* W_uq  = (const float*)d_in[2];
    const float* W_dkv = (const float*)d_in[3];
    const float* W_uk  = (const float*)d_in[4];
    const float* W_uv  = (const float*)d_in[5];
    const float* W_o   = (const float*)d_in[6];
    float* out = (float*)d_out;

    char* ws = (char*)d_ws;
    u16* xb      = (u16*)(ws);                          // 8 MB   [4096][1024]
    u16* c_qkv   = (u16*)(ws + (8u << 20));             // 4 MB   [4096][512]
    u16* Qb      = (u16*)(ws + (12u << 20));            // 8 MB   [4096][1024]
    u16* KVb     = (u16*)(ws + (20u << 20));            // 16 MB  [4096][2048]
    u16* Vt      = (u16*)(ws + (36u << 20));            // 8 MB   [2048][2048]
    u16* attno   = (u16*)(ws + (44u << 20));            // 8 MB   [4096][1024]
    u16* Wdqkv_t = (u16*)(ws + (52u << 20));            // 1 MB   [512][1024]
    u16* Wuq_t   = (u16*)(ws + (53u << 20));            // 0.5 MB [1024][256]
    u16* Wukv_t  = (u16*)(ws + (53u << 20) + (512u << 10)); // 1 MB [2048][256]
    u16* Wo_t    = (u16*)(ws + (55u << 20));            // 2 MB   [1024][1024]

    dim3 blk(256);
    prep<<<dim3(32, 32, 7), blk, 0, stream>>>(x, xb, W_dq, W_dkv, W_uq, W_uk, W_uv, W_o,
        Wdqkv_t, Wdqkv_t + 256 * 1024, Wuq_t, Wukv_t, Wukv_t + 1024 * 256, Wo_t);
    // c_qkv = x @ [W_dq | W_dkv]        [4096,512] K=1024
    gemmT<64, true><<<dim3(8, 32), blk, 0, stream>>>(xb, DM, Wdqkv_t, DM, c_qkv, 512, DM);
    // Q | KV up-projection fused        K=256
    gemm_qkv<<<dim3(24, 32), blk, 0, stream>>>(c_qkv, Wuq_t, Wukv_t, Qb, KVb);
    // Vt[b*16+h][dk][s] = V[b*2048+s][h*64+dk]
    vt_kernel<<<dim3(32, 64, 2), blk, 0, stream>>>(KVb, Vt);
    // attention: 1024 blocks, pair-parity split, uniform CU-load mapping
    attn_mfma7<<<dim3(1024), blk, 0, stream>>>(Qb, KVb, Vt, attno);
    // out = attno @ W_o                 [4096,1024] K=1024, fp32 out
    gemmT<128, false><<<dim3(8, 32), blk, 0, stream>>>(attno, DM, Wo_t, DM, out, DM, DM);
}

// Round 11
// 128.483 us; speedup vs baseline: 1.3301x; 1.3301x over previous
//
#include <hip/hip_runtime.h>
#include <math.h>

#define AS3 __attribute__((address_space(3)))
#define AS1 __attribute__((address_space(1)))

typedef unsigned short u16;
typedef unsigned int u32;
typedef __bf16 bf16_t;
typedef bf16_t bf16x8 __attribute__((ext_vector_type(8)));
typedef float f32x4 __attribute__((ext_vector_type(4)));
typedef float f32x16 __attribute__((ext_vector_type(16)));
typedef unsigned short u16x4 __attribute__((ext_vector_type(4)));
typedef unsigned short u16x8 __attribute__((ext_vector_type(8)));
typedef unsigned int u32x4 __attribute__((ext_vector_type(4)));

#define NH 16
#define DK 64
#define DC 256
#define DM 1024
#define BB 2
#define SS 2048
#define TT (BB*SS)

__device__ __forceinline__ u16 f2bf(float f) {
    unsigned u = __builtin_bit_cast(unsigned, f);
    unsigned r = (u + 0x7FFFu + ((u >> 16) & 1u)) >> 16;
    return (u16)r;
}

__device__ __forceinline__ u32 cvtpk_bf16(float a, float b) {
    u32 d;
    asm("v_cvt_pk_bf16_f32 %0, %1, %2" : "=v"(d) : "v"(a), "v"(b));
    return d;
}

__device__ __forceinline__ bf16x8 lds_frag(const char* p) {
    return __builtin_bit_cast(bf16x8, *reinterpret_cast<const u16x8*>(p));
}

// ---------------- fused prep: x->bf16 (z=6) + 6 weight transposes (z=0..5) ----------------
__global__ __launch_bounds__(256) void prep(const float* __restrict__ x, u16* __restrict__ xb,
                                            const float* w0, const float* w1, const float* w2,
                                            const float* w3, const float* w4, const float* w5,
                                            u16* d0, u16* d1, u16* d2, u16* d3, u16* d4, u16* d5) {
    __shared__ float t[32][33];
    const int z = blockIdx.z;
    if (z == 6) {
        int blk = blockIdx.y * 32 + blockIdx.x;
        int i = (blk * 256 + threadIdx.x) * 16;
        float4 v0 = *reinterpret_cast<const float4*>(x + i);
        float4 v1 = *reinterpret_cast<const float4*>(x + i + 4);
        float4 v2 = *reinterpret_cast<const float4*>(x + i + 8);
        float4 v3 = *reinterpret_cast<const float4*>(x + i + 12);
        u16x8 o0, o1;
        o0[0] = f2bf(v0.x); o0[1] = f2bf(v0.y); o0[2] = f2bf(v0.z); o0[3] = f2bf(v0.w);
        o0[4] = f2bf(v1.x); o0[5] = f2bf(v1.y); o0[6] = f2bf(v1.z); o0[7] = f2bf(v1.w);
        o1[0] = f2bf(v2.x); o1[1] = f2bf(v2.y); o1[2] = f2bf(v2.z); o1[3] = f2bf(v2.w);
        o1[4] = f2bf(v3.x); o1[5] = f2bf(v3.y); o1[6] = f2bf(v3.z); o1[7] = f2bf(v3.w);
        *reinterpret_cast<u16x8*>(xb + i) = o0;
        *reinterpret_cast<u16x8*>(xb + i + 8) = o1;
        return;
    }
    const float* src; u16* dst; int R, C, opitch;
    switch (z) {
        case 0:  src = w0; dst = d0; R = 1024; C = 256;  opitch = 1024; break;
        case 1:  src = w1; dst = d1; R = 1024; C = 256;  opitch = 1024; break;
        case 2:  src = w2; dst = d2; R = 256;  C = 1024; opitch = 256;  break;
        case 3:  src = w3; dst = d3; R = 256;  C = 1024; opitch = 256;  break;
        case 4:  src = w4; dst = d4; R = 256;  C = 1024; opitch = 256;  break;
        default: src = w5; dst = d5; R = 1024; C = 1024; opitch = 1024; break;
    }
    int c0 = blockIdx.x * 32, r0 = blockIdx.y * 32;
    if (c0 >= C || r0 >= R) return;
    int tx = threadIdx.x & 31, ty = threadIdx.x >> 5;
    #pragma unroll
    for (int p = 0; p < 4; ++p)
        t[ty + 8 * p][tx] = src[(r0 + ty + 8 * p) * C + c0 + tx];
    __syncthreads();
    #pragma unroll
    for (int p = 0; p < 4; ++p)
        dst[(c0 + ty + 8 * p) * opitch + r0 + tx] = f2bf(t[tx][ty + 8 * p]);
}

// ---------------- MFMA GEMM body: C[128 x BN] tile at (bm, bn) ----------------
// OUT_MODE: 0 = f32 normal, 1 = bf16 normal, 2 = bf16 transposed into Vt
// (mode 2: C row r (= b*2048+s) col c (= v-dim) -> Vt[(r>>11)*1024 + c][r&2047])
template <int BN, int OUT_MODE>
__device__ __forceinline__ void gemm_body(const u16* __restrict__ A, int lda,
                                          const u16* __restrict__ Bt, int ldb,
                                          void* __restrict__ C, int ldc, int K,
                                          int bm, int bn, u16* As, u16* Bs) {
    constexpr int NF = BN / 32;
    constexpr int BI = BN / 64;
    const int tid = threadIdx.x;
    const int lane = tid & 63;
    const int w = tid >> 6;
    const int wr = w >> 1, wc = w & 1;
    const int l15 = lane & 15, l4 = lane >> 4;

    f32x4 acc[4][NF] = {};

    for (int k0 = 0; k0 < K; k0 += 32) {
        #pragma unroll
        for (int i = 0; i < 2; ++i) {
            int db = i * 4096 + tid * 16;
            int row = db >> 6;
            int kc = (db & 63) >> 1;
            __builtin_amdgcn_global_load_lds(
                (const AS1 void*)(A + (bm + row) * lda + k0 + kc),
                (AS3 void*)((AS3 char*)(AS3 void*)As + i * 4096 + w * 1024), 16, 0, 0);
        }
        #pragma unroll
        for (int i = 0; i < BI; ++i) {
            int db = i * 4096 + tid * 16;
            int row = db >> 6;
            int kc = (db & 63) >> 1;
            __builtin_amdgcn_global_load_lds(
                (const AS1 void*)(Bt + (bn + row) * ldb + k0 + kc),
                (AS3 void*)((AS3 char*)(AS3 void*)Bs + i * 4096 + w * 1024), 16, 0, 0);
        }
        __syncthreads();
        bf16x8 a[4], b[NF];
        #pragma unroll
        for (int m = 0; m < 4; ++m)
            a[m] = __builtin_bit_cast(bf16x8,
                *reinterpret_cast<const u16x8*>(&As[(wr * 64 + m * 16 + l15) * 32 + l4 * 8]));
        #pragma unroll
        for (int n = 0; n < NF; ++n)
            b[n] = __builtin_bit_cast(bf16x8,
                *reinterpret_cast<const u16x8*>(&Bs[(wc * (BN / 2) + n * 16 + l15) * 32 + l4 * 8]));
        #pragma unroll
        for (int m = 0; m < 4; ++m)
            #pragma unroll
            for (int n = 0; n < NF; ++n)
                acc[m][n] = __builtin_amdgcn_mfma_f32_16x16x32_bf16(a[m], b[n], acc[m][n], 0, 0, 0);
        __syncthreads();
    }
    if (OUT_MODE == 2) {
        // transposed store: per (m,n), j=0..3 are consecutive s positions of one Vt row
        #pragma unroll
        for (int m = 0; m < 4; ++m) {
            int row = bm + wr * 64 + m * 16 + l4 * 4;   // = b*2048 + s, s%4==0
            int vrow_base = (row >> 11) << 10;
            int scol = row & 2047;
            #pragma unroll
            for (int n = 0; n < NF; ++n) {
                int col = bn + wc * (BN / 2) + n * 16 + l15;   // v-dim
                u16x4 ov;
                ov[0] = f2bf(acc[m][n][0]); ov[1] = f2bf(acc[m][n][1]);
                ov[2] = f2bf(acc[m][n][2]); ov[3] = f2bf(acc[m][n][3]);
                *reinterpret_cast<u16x4*>((u16*)C + (size_t)(vrow_base + col) * 2048 + scol) = ov;
            }
        }
    } else {
        #pragma unroll
        for (int m = 0; m < 4; ++m) {
            int row = bm + wr * 64 + m * 16 + l4 * 4;
            #pragma unroll
            for (int j = 0; j < 4; ++j) {
                #pragma unroll
                for (int n = 0; n < NF; ++n) {
                    int col = bn + wc * (BN / 2) + n * 16 + l15;
                    if (OUT_MODE == 1)
                        ((u16*)C)[(row + j) * ldc + col] = f2bf(acc[m][n][j]);
                    else
                        ((float*)C)[(row + j) * ldc + col] = acc[m][n][j];
                }
            }
        }
    }
}

template <int BN, int OUT_MODE>
__global__ __launch_bounds__(256) void gemmT(const u16* __restrict__ A, int lda,
                                             const u16* __restrict__ Bt, int ldb,
                                             void* __restrict__ C, int ldc, int K) {
    __shared__ u16 As[128 * 32];
    __shared__ u16 Bs[BN * 32];
    gemm_body<BN, OUT_MODE>(A, lda, Bt, ldb, C, ldc, K, blockIdx.y * 128, blockIdx.x * BN, As, Bs);
}

// fused Q + K + V up-projection, K=256:
//   bx 0..7  -> Q tile   (Qb [4096][1024])
//   bx 8..15 -> K tile   (Kb [4096][1024], K-only)
//   bx 16..23-> V tile   (written transposed into Vt [2048][2048])
__global__ __launch_bounds__(256) void gemm_qkv(const u16* __restrict__ c_qkv,
                                                const u16* __restrict__ Wuq_t,
                                                const u16* __restrict__ Wukv_t,
                                                u16* __restrict__ Qb, u16* __restrict__ Kb,
                                                u16* __restrict__ Vt) {
    __shared__ u16 As[128 * 32];
    __shared__ u16 Bs[128 * 32];
    const int bx = blockIdx.x;
    if (bx < 8) {
        gemm_body<128, 1>(c_qkv, 512, Wuq_t, 256, Qb, 1024, 256,
                          blockIdx.y * 128, bx * 128, As, Bs);
    } else if (bx < 16) {
        gemm_body<128, 1>(c_qkv + 256, 512, Wukv_t, 256, Kb, 1024, 256,
                          blockIdx.y * 128, (bx - 8) * 128, As, Bs);
    } else {
        gemm_body<128, 2>(c_qkv + 256, 512, Wukv_t + 1024 * 256, 256, Vt, 0, 256,
                          blockIdx.y * 128, (bx - 16) * 128, As, Bs);
    }
}

// ---------------- MFMA causal flash attention (R9-verified, Kb pitch 1024) ----------------
// Block = (bq 64 q-rows, bh). Waves {0,1} even key-tiles, {2,3} odd; wave owns
// 32 q-rows. K/V LDS-staged per tile, double-buffered, one barrier per round.
__global__ __launch_bounds__(256) void attn_mfma6(const u16* __restrict__ Qb,
                                                  const u16* __restrict__ Kb,
                                                  const u16* __restrict__ VtG,
                                                  u16* __restrict__ O) {
    __shared__ char lds[65536];   // 4 slots (cur,pair) x (8KB K + 8KB V); aliased by combine
    const int bid = blockIdx.x;
    const int bq = 31 - (bid >> 5);      // big jobs dispatch first
    const int bh = bid & 31;
    const int b = bh >> 4, head = bh & 15;
    const int tid = threadIdx.x;
    const int w = tid >> 6;
    const int lane = tid & 63;
    const int l31 = lane & 31, hi = lane >> 5;
    const int r7 = l31 & 7;
    const int pair = w >> 1, sub = w & 1;
    const int q0 = bq * 64;
    const int qg = q0 + sub * 32 + l31;
    const int rounds = (bq >> 1) + 1;
    const float c2 = 0.125f * 1.44269504088896340736f;  // scale * log2(e)
    const float THRraw = 44.3614195558f;                // 8 / c2

    // Q fragments (B-operand): Q[q][16kc + 8hi + 0..7]
    bf16x8 qf[4];
    {
        const u16* qp = Qb + (size_t)(b * SS + qg) * 1024 + head * 64 + hi * 8;
        #pragma unroll
        for (int kc = 0; kc < 4; ++kc)
            qf[kc] = __builtin_bit_cast(bf16x8, *reinterpret_cast<const u16x8*>(qp + kc * 16));
    }

    f32x16 acc0 = {}, acc1 = {};   // O^T partial: d rows (0..31 / 32..63), col = q
    float mrow = -3.0e38f, lrow = 0.f;

#define STAGE2(cur_, r_) do { \
    _Pragma("unroll") \
    for (int p_ = 0; p_ < 2; ++p_) { \
        int kt_ = 2 * (r_) + p_; \
        if (kt_ <= bq) { \
            int k0_ = kt_ * 64; \
            char* base_ = lds + (((cur_) << 1) | p_) * 16384; \
            _Pragma("unroll") \
            for (int c_ = 0; c_ < 2; ++c_) { \
                int i_ = tid + 256 * c_; int row_ = i_ >> 3; int sc_ = (i_ & 7) ^ (row_ & 7); \
                __builtin_amdgcn_global_load_lds( \
                    (const AS1 void*)(Kb + (size_t)(b * SS + k0_ + row_) * 1024 + head * 64 + sc_ * 8), \
                    (AS3 void*)((AS3 char*)(AS3 void*)base_ + c_ * 4096 + w * 1024), 16, 0, 0); \
                __builtin_amdgcn_global_load_lds( \
                    (const AS1 void*)(VtG + (size_t)(bh * 64 + row_) * 2048 + k0_ + sc_ * 8), \
                    (AS3 void*)((AS3 char*)(AS3 void*)base_ + 8192 + c_ * 4096 + w * 1024), 16, 0, 0); \
            } \
        } \
    } } while (0)

    int cur = 0;
    STAGE2(0, 0);
    __syncthreads();

    for (int r = 0; r < rounds; ++r) {
        if (r + 1 < rounds) STAGE2(cur ^ 1, r + 1);
        const int kt = 2 * r + pair;
        if (kt <= bq) {
            const char* Kb_ = lds + ((cur << 1) | pair) * 16384;
            const char* Vb_ = Kb_ + 8192;
            const int k0 = kt * 64;
            // S^T = K @ Q^T
            f32x16 s0 = {}, s1 = {};
            __builtin_amdgcn_s_setprio(1);
            #pragma unroll
            for (int kc = 0; kc < 4; ++kc) {
                bf16x8 kf0 = lds_frag(Kb_ + (l31) * 128 + ((2 * kc + hi) ^ r7) * 16);
                bf16x8 kf1 = lds_frag(Kb_ + (32 + l31) * 128 + ((2 * kc + hi) ^ r7) * 16);
                s0 = __builtin_amdgcn_mfma_f32_32x32x16_bf16(kf0, qf[kc], s0, 0, 0, 0);
                s1 = __builtin_amdgcn_mfma_f32_32x32x16_bf16(kf1, qf[kc], s1, 0, 0, 0);
            }
            __builtin_amdgcn_s_setprio(0);
            if (kt == bq) {   // diagonal tile: causal mask
                const int lim = qg - k0 - hi * 4;
                #pragma unroll
                for (int r2 = 0; r2 < 16; ++r2) {
                    const int ko = (r2 & 3) + 8 * (r2 >> 2);
                    s0[r2] = (ko > lim) ? -3.0e38f : s0[r2];
                    s1[r2] = (ko + 32 > lim) ? -3.0e38f : s1[r2];
                }
            }
            // tree max + cross-half exchange
            float a8[8];
            #pragma unroll
            for (int i = 0; i < 8; ++i)
                a8[i] = fmaxf(fmaxf(s0[2 * i], s0[2 * i + 1]), fmaxf(s1[2 * i], s1[2 * i + 1]));
            float tm = fmaxf(fmaxf(fmaxf(a8[0], a8[1]), fmaxf(a8[2], a8[3])),
                             fmaxf(fmaxf(a8[4], a8[5]), fmaxf(a8[6], a8[7])));
            tm = fmaxf(tm, __shfl_xor(tm, 32));
            // defer-max
            bool nofix = __all(tm <= mrow + THRraw);
            float scale = 1.f;
            if (!nofix) {
                float mnew = fmaxf(mrow, tm);
                scale = exp2f((mrow - mnew) * c2);
                mrow = mnew;
            }
            float mc = mrow * c2;
            #pragma unroll
            for (int r2 = 0; r2 < 16; ++r2) {
                s0[r2] = exp2f(__builtin_fmaf(s0[r2], c2, -mc));
                s1[r2] = exp2f(__builtin_fmaf(s1[r2], c2, -mc));
            }
            float c8[8];
            #pragma unroll
            for (int i = 0; i < 8; ++i)
                c8[i] = (s0[2 * i] + s0[2 * i + 1]) + (s1[2 * i] + s1[2 * i + 1]);
            float rsum = ((c8[0] + c8[1]) + (c8[2] + c8[3])) + ((c8[4] + c8[5]) + (c8[6] + c8[7]));
            rsum += __shfl_xor(rsum, 32);
            if (nofix) {
                lrow += rsum;
            } else {
                lrow = lrow * scale + rsum;
                #pragma unroll
                for (int r2 = 0; r2 < 16; ++r2) { acc0[r2] *= scale; acc1[r2] *= scale; }
            }
            // pack P to bf16 pairs
            u32 cg0[4][2], cg1[4][2];
            #pragma unroll
            for (int g = 0; g < 4; ++g) {
                #pragma unroll
                for (int w2 = 0; w2 < 2; ++w2) {
                    cg0[g][w2] = cvtpk_bf16(s0[4 * g + 2 * w2], s0[4 * g + 2 * w2 + 1]);
                    cg1[g][w2] = cvtpk_bf16(s1[4 * g + 2 * w2], s1[4 * g + 2 * w2 + 1]);
                }
            }
            // assemble P frags via shfl_xor(32): pa[ks] = P[q][16ks + 8hi + 0..7]
            bf16x8 pa[4];
            #pragma unroll
            for (int ks = 0; ks < 4; ++ks) {
                const int g0 = (2 * ks) & 3, g1 = g0 + 1;
                u32 a0, a1, b0, b1;
                if (ks < 2) { a0 = cg0[g0][0]; a1 = cg0[g0][1]; b0 = cg0[g1][0]; b1 = cg0[g1][1]; }
                else        { a0 = cg1[g0][0]; a1 = cg1[g0][1]; b0 = cg1[g1][0]; b1 = cg1[g1][1]; }
                u32 pa0 = (u32)__shfl_xor((int)a0, 32);
                u32 pa1 = (u32)__shfl_xor((int)a1, 32);
                u32 pb0 = (u32)__shfl_xor((int)b0, 32);
                u32 pb1 = (u32)__shfl_xor((int)b1, 32);
                u32x4 f;
                f.x = hi ? pb0 : a0;
                f.y = hi ? pb1 : a1;
                f.z = hi ? b0 : pa0;
                f.w = hi ? b1 : pa1;
                pa[ks] = __builtin_bit_cast(bf16x8, f);
            }
            // O^T += V^T @ P^T
            __builtin_amdgcn_s_setprio(1);
            #pragma unroll
            for (int ks = 0; ks < 4; ++ks) {
                bf16x8 vf0 = lds_frag(Vb_ + (l31) * 128 + ((2 * ks + hi) ^ r7) * 16);
                bf16x8 vf1 = lds_frag(Vb_ + (32 + l31) * 128 + ((2 * ks + hi) ^ r7) * 16);
                acc0 = __builtin_amdgcn_mfma_f32_32x32x16_bf16(vf0, pa[ks], acc0, 0, 0, 0);
                acc1 = __builtin_amdgcn_mfma_f32_32x32x16_bf16(vf1, pa[ks], acc1, 0, 0, 0);
            }
            __builtin_amdgcn_s_setprio(0);
        }
        __syncthreads();
        cur ^= 1;
    }
#undef STAGE2

    // write partials to LDS (aliases staging region; all compute done)
    float* part = (float*)lds;                    // [4][32][65]
    float* mls  = (float*)(lds + 33280);          // [4][2][32]
    #pragma unroll
    for (int r2 = 0; r2 < 16; ++r2) {
        const int d = (r2 & 3) + 8 * (r2 >> 2) + 4 * hi;
        part[(w * 32 + l31) * 65 + d] = acc0[r2];
        part[(w * 32 + l31) * 65 + d + 32] = acc1[r2];
    }
    if (hi == 0) {
        mls[(w * 2 + 0) * 32 + l31] = mrow;
        mls[(w * 2 + 1) * 32 + l31] = lrow;
    }
    __syncthreads();

    // combine 2 partials: thread -> q = tid>>2 (0..63), d-seg = (tid&3)*16
    {
        const int q = tid >> 2, ds0 = (tid & 3) * 16;
        const int s_ = q >> 5, qq = q & 31;
        const int wa_ = s_, wb_ = 2 + s_;
        float ma = mls[(wa_ * 2 + 0) * 32 + qq], la = mls[(wa_ * 2 + 1) * 32 + qq];
        float mb = mls[(wb_ * 2 + 0) * 32 + qq], lb = mls[(wb_ * 2 + 1) * 32 + qq];
        float mt = fmaxf(ma, mb);
        float wa = exp2f((ma - mt) * c2);
        float wb = exp2f((mb - mt) * c2);
        float lt = la * wa + lb * wb;
        float inv = 1.0f / lt;
        u16x8 ov0, ov1;
        #pragma unroll
        for (int i = 0; i < 8; ++i) {
            float v0 = part[(wa_ * 32 + qq) * 65 + ds0 + i] * wa +
                       part[(wb_ * 32 + qq) * 65 + ds0 + i] * wb;
            float v1 = part[(wa_ * 32 + qq) * 65 + ds0 + 8 + i] * wa +
                       part[(wb_ * 32 + qq) * 65 + ds0 + 8 + i] * wb;
            ov0[i] = f2bf(v0 * inv);
            ov1[i] = f2bf(v1 * inv);
        }
        u16* op = O + (size_t)(b * SS + q0 + q) * 1024 + head * 64 + ds0;
        *reinterpret_cast<u16x8*>(op) = ov0;
        *reinterpret_cast<u16x8*>(op + 8) = ov1;
    }
}

// ---------------- launch ----------------

extern "C" void kernel_launch(void* const* d_in, const int* in_sizes, int n_in,
                              void* d_out, int out_size, void* d_ws, size_t ws_size,
                              hipStream_t stream) {
    const float* x     = (const float*)d_in[0];
    const float* W_dq  = (const float*)d_in[1];
    const float* W_uq  = (const float*)d_in[2];
    const float* W_dkv = (const float*)d_in[3];
    const float* W_uk  = (const float*)d_in[4];
    const float* W_uv  = (const float*)d_in[5];
    const float* W_o   = (const float*)d_in[6];
    float* out = (float*)d_out;

    char* ws = (char*)d_ws;
    u16* xb      = (u16*)(ws);                          // 8 MB   [4096][1024]
    u16* c_qkv   = (u16*)(ws + (8u << 20));             // 4 MB   [4096][512]
    u16* Qb      = (u16*)(ws + (12u << 20));            // 8 MB   [4096][1024]
    u16* Kb      = (u16*)(ws + (20u << 20));            // 8 MB   [4096][1024] (K only)
    u16* Vt      = (u16*)(ws + (36u << 20));            // 8 MB   [2048][2048]
    u16* attno   = (u16*)(ws + (44u << 20));            // 8 MB   [4096][1024]
    u16* Wdqkv_t = (u16*)(ws + (52u << 20));            // 1 MB   [512][1024]
    u16* Wuq_t   = (u16*)(ws + (53u << 20));            // 0.5 MB [1024][256]
    u16* Wukv_t  = (u16*)(ws + (53u << 20) + (512u << 10)); // 1 MB [2048][256]
    u16* Wo_t    = (u16*)(ws + (55u << 20));            // 2 MB   [1024][1024]

    dim3 blk(256);
    prep<<<dim3(32, 32, 7), blk, 0, stream>>>(x, xb, W_dq, W_dkv, W_uq, W_uk, W_uv, W_o,
        Wdqkv_t, Wdqkv_t + 256 * 1024, Wuq_t, Wukv_t, Wukv_t + 1024 * 256, Wo_t);
    // c_qkv = x @ [W_dq | W_dkv]        [4096,512] K=1024
    gemmT<64, 1><<<dim3(8, 32), blk, 0, stream>>>(xb, DM, Wdqkv_t, DM, c_qkv, 512, DM);
    // Q | K | V(transposed) up-projection, K=256
    gemm_qkv<<<dim3(24, 32), blk, 0, stream>>>(c_qkv, Wuq_t, Wukv_t, Qb, Kb, Vt);
    // attention: 1024 blocks, pair-parity split, LPT order
    attn_mfma6<<<dim3(1024), blk, 0, stream>>>(Qb, Kb, Vt, attno);
    // out = attno @ W_o                 [4096,1024] K=1024, fp32 out
    gemmT<128, 0><<<dim3(8, 32), blk, 0, stream>>>(attno, DM, Wo_t, DM, out, DM, DM);
}

// Round 12
// 118.741 us; speedup vs baseline: 1.4392x; 1.0820x over previous
//
#include <hip/hip_runtime.h>
#include <math.h>

#define AS3 __attribute__((address_space(3)))
#define AS1 __attribute__((address_space(1)))

typedef unsigned short u16;
typedef unsigned int u32;
typedef __bf16 bf16_t;
typedef bf16_t bf16x8 __attribute__((ext_vector_type(8)));
typedef float f32x4 __attribute__((ext_vector_type(4)));
typedef float f32x16 __attribute__((ext_vector_type(16)));
typedef unsigned short u16x4 __attribute__((ext_vector_type(4)));
typedef unsigned short u16x8 __attribute__((ext_vector_type(8)));
typedef unsigned int u32x4 __attribute__((ext_vector_type(4)));

#define NH 16
#define DK 64
#define DC 256
#define DM 1024
#define BB 2
#define SS 2048
#define TT (BB*SS)

__device__ __forceinline__ u16 f2bf(float f) {
    unsigned u = __builtin_bit_cast(unsigned, f);
    unsigned r = (u + 0x7FFFu + ((u >> 16) & 1u)) >> 16;
    return (u16)r;
}

__device__ __forceinline__ u32 cvtpk_bf16(float a, float b) {
    u32 d;
    asm("v_cvt_pk_bf16_f32 %0, %1, %2" : "=v"(d) : "v"(a), "v"(b));
    return d;
}

__device__ __forceinline__ bf16x8 lds_frag(const char* p) {
    return __builtin_bit_cast(bf16x8, *reinterpret_cast<const u16x8*>(p));
}

// ---------------- fused prep: x->bf16 (z=6) + 6 weight transposes (z=0..5) ----------------
__global__ __launch_bounds__(256) void prep(const float* __restrict__ x, u16* __restrict__ xb,
                                            const float* w0, const float* w1, const float* w2,
                                            const float* w3, const float* w4, const float* w5,
                                            u16* d0, u16* d1, u16* d2, u16* d3, u16* d4, u16* d5) {
    __shared__ float t[32][33];
    const int z = blockIdx.z;
    if (z == 6) {
        int blk = blockIdx.y * 32 + blockIdx.x;
        int i = (blk * 256 + threadIdx.x) * 16;
        float4 v0 = *reinterpret_cast<const float4*>(x + i);
        float4 v1 = *reinterpret_cast<const float4*>(x + i + 4);
        float4 v2 = *reinterpret_cast<const float4*>(x + i + 8);
        float4 v3 = *reinterpret_cast<const float4*>(x + i + 12);
        u16x8 o0, o1;
        o0[0] = f2bf(v0.x); o0[1] = f2bf(v0.y); o0[2] = f2bf(v0.z); o0[3] = f2bf(v0.w);
        o0[4] = f2bf(v1.x); o0[5] = f2bf(v1.y); o0[6] = f2bf(v1.z); o0[7] = f2bf(v1.w);
        o1[0] = f2bf(v2.x); o1[1] = f2bf(v2.y); o1[2] = f2bf(v2.z); o1[3] = f2bf(v2.w);
        o1[4] = f2bf(v3.x); o1[5] = f2bf(v3.y); o1[6] = f2bf(v3.z); o1[7] = f2bf(v3.w);
        *reinterpret_cast<u16x8*>(xb + i) = o0;
        *reinterpret_cast<u16x8*>(xb + i + 8) = o1;
        return;
    }
    const float* src; u16* dst; int R, C, opitch;
    switch (z) {
        case 0:  src = w0; dst = d0; R = 1024; C = 256;  opitch = 1024; break;
        case 1:  src = w1; dst = d1; R = 1024; C = 256;  opitch = 1024; break;
        case 2:  src = w2; dst = d2; R = 256;  C = 1024; opitch = 256;  break;
        case 3:  src = w3; dst = d3; R = 256;  C = 1024; opitch = 256;  break;
        case 4:  src = w4; dst = d4; R = 256;  C = 1024; opitch = 256;  break;
        default: src = w5; dst = d5; R = 1024; C = 1024; opitch = 1024; break;
    }
    int c0 = blockIdx.x * 32, r0 = blockIdx.y * 32;
    if (c0 >= C || r0 >= R) return;
    int tx = threadIdx.x & 31, ty = threadIdx.x >> 5;
    #pragma unroll
    for (int p = 0; p < 4; ++p)
        t[ty + 8 * p][tx] = src[(r0 + ty + 8 * p) * C + c0 + tx];
    __syncthreads();
    #pragma unroll
    for (int p = 0; p < 4; ++p)
        dst[(c0 + ty + 8 * p) * opitch + r0 + tx] = f2bf(t[tx][ty + 8 * p]);
}

// ---------------- MFMA GEMM body: C[BM x BN] tile at (bm, bn) ----------------
// 4 waves as 2x2; wave covers (BM/2)x(BN/2). MF=BM/32, NF=BN/32 frags.
// OUT_MODE: 0 = f32 normal, 1 = bf16 normal, 2 = bf16 transposed into Vt
template <int BM, int BN, int OUT_MODE>
__device__ __forceinline__ void gemm_body(const u16* __restrict__ A, int lda,
                                          const u16* __restrict__ Bt, int ldb,
                                          void* __restrict__ C, int ldc, int K,
                                          int bm, int bn, u16* As, u16* Bs) {
    constexpr int MF = BM / 32;
    constexpr int NF = BN / 32;
    constexpr int AI = BM / 64;
    constexpr int BI = BN / 64;
    const int tid = threadIdx.x;
    const int lane = tid & 63;
    const int w = tid >> 6;
    const int wr = w >> 1, wc = w & 1;
    const int l15 = lane & 15, l4 = lane >> 4;

    f32x4 acc[MF][NF] = {};

    for (int k0 = 0; k0 < K; k0 += 32) {
        #pragma unroll
        for (int i = 0; i < AI; ++i) {
            int db = i * 4096 + tid * 16;
            int row = db >> 6;
            int kc = (db & 63) >> 1;
            __builtin_amdgcn_global_load_lds(
                (const AS1 void*)(A + (bm + row) * lda + k0 + kc),
                (AS3 void*)((AS3 char*)(AS3 void*)As + i * 4096 + w * 1024), 16, 0, 0);
        }
        #pragma unroll
        for (int i = 0; i < BI; ++i) {
            int db = i * 4096 + tid * 16;
            int row = db >> 6;
            int kc = (db & 63) >> 1;
            __builtin_amdgcn_global_load_lds(
                (const AS1 void*)(Bt + (bn + row) * ldb + k0 + kc),
                (AS3 void*)((AS3 char*)(AS3 void*)Bs + i * 4096 + w * 1024), 16, 0, 0);
        }
        __syncthreads();
        bf16x8 a[MF], b[NF];
        #pragma unroll
        for (int m = 0; m < MF; ++m)
            a[m] = __builtin_bit_cast(bf16x8,
                *reinterpret_cast<const u16x8*>(&As[(wr * (BM / 2) + m * 16 + l15) * 32 + l4 * 8]));
        #pragma unroll
        for (int n = 0; n < NF; ++n)
            b[n] = __builtin_bit_cast(bf16x8,
                *reinterpret_cast<const u16x8*>(&Bs[(wc * (BN / 2) + n * 16 + l15) * 32 + l4 * 8]));
        #pragma unroll
        for (int m = 0; m < MF; ++m)
            #pragma unroll
            for (int n = 0; n < NF; ++n)
                acc[m][n] = __builtin_amdgcn_mfma_f32_16x16x32_bf16(a[m], b[n], acc[m][n], 0, 0, 0);
        __syncthreads();
    }
    if (OUT_MODE == 2) {
        // transposed store: per (m,n), j=0..3 are consecutive s positions of one Vt row
        #pragma unroll
        for (int m = 0; m < MF; ++m) {
            int row = bm + wr * (BM / 2) + m * 16 + l4 * 4;   // = b*2048 + s, s%4==0
            int vrow_base = (row >> 11) << 10;
            int scol = row & 2047;
            #pragma unroll
            for (int n = 0; n < NF; ++n) {
                int col = bn + wc * (BN / 2) + n * 16 + l15;   // v-dim
                u16x4 ov;
                ov[0] = f2bf(acc[m][n][0]); ov[1] = f2bf(acc[m][n][1]);
                ov[2] = f2bf(acc[m][n][2]); ov[3] = f2bf(acc[m][n][3]);
                *reinterpret_cast<u16x4*>((u16*)C + (size_t)(vrow_base + col) * 2048 + scol) = ov;
            }
        }
    } else {
        #pragma unroll
        for (int m = 0; m < MF; ++m) {
            int row = bm + wr * (BM / 2) + m * 16 + l4 * 4;
            #pragma unroll
            for (int j = 0; j < 4; ++j) {
                #pragma unroll
                for (int n = 0; n < NF; ++n) {
                    int col = bn + wc * (BN / 2) + n * 16 + l15;
                    if (OUT_MODE == 1)
                        ((u16*)C)[(row + j) * ldc + col] = f2bf(acc[m][n][j]);
                    else
                        ((float*)C)[(row + j) * ldc + col] = acc[m][n][j];
                }
            }
        }
    }
}

template <int BM, int BN, int OUT_MODE>
__global__ __launch_bounds__(256) void gemmT(const u16* __restrict__ A, int lda,
                                             const u16* __restrict__ Bt, int ldb,
                                             void* __restrict__ C, int ldc, int K) {
    __shared__ u16 As[BM * 32];
    __shared__ u16 Bs[BN * 32];
    gemm_body<BM, BN, OUT_MODE>(A, lda, Bt, ldb, C, ldc, K,
                                blockIdx.y * BM, blockIdx.x * BN, As, Bs);
}

// fused Q + K + V up-projection, K=256:
//   bx 0..7  -> Q tile   (Qb [4096][1024])
//   bx 8..15 -> K tile   (Kb [4096][1024], K-only)
//   bx 16..23-> V tile   (written transposed into Vt [2048][2048])
__global__ __launch_bounds__(256) void gemm_qkv(const u16* __restrict__ c_qkv,
                                                const u16* __restrict__ Wuq_t,
                                                const u16* __restrict__ Wukv_t,
                                                u16* __restrict__ Qb, u16* __restrict__ Kb,
                                                u16* __restrict__ Vt) {
    __shared__ u16 As[128 * 32];
    __shared__ u16 Bs[128 * 32];
    const int bx = blockIdx.x;
    if (bx < 8) {
        gemm_body<128, 128, 1>(c_qkv, 512, Wuq_t, 256, Qb, 1024, 256,
                               blockIdx.y * 128, bx * 128, As, Bs);
    } else if (bx < 16) {
        gemm_body<128, 128, 1>(c_qkv + 256, 512, Wukv_t, 256, Kb, 1024, 256,
                               blockIdx.y * 128, (bx - 8) * 128, As, Bs);
    } else {
        gemm_body<128, 128, 2>(c_qkv + 256, 512, Wukv_t + 1024 * 256, 256, Vt, 0, 256,
                               blockIdx.y * 128, (bx - 16) * 128, As, Bs);
    }
}

// ---------------- MFMA causal flash attention (R9/R11-verified) ----------------
// Block = (bq 64 q-rows, bh). Waves {0,1} even key-tiles, {2,3} odd; wave owns
// 32 q-rows. K/V LDS-staged per tile, double-buffered, one barrier per round.
__global__ __launch_bounds__(256) void attn_mfma6(const u16* __restrict__ Qb,
                                                  const u16* __restrict__ Kb,
                                                  const u16* __restrict__ VtG,
                                                  u16* __restrict__ O) {
    __shared__ char lds[65536];   // 4 slots (cur,pair) x (8KB K + 8KB V); aliased by combine
    const int bid = blockIdx.x;
    const int bq = 31 - (bid >> 5);      // big jobs dispatch first
    const int bh = bid & 31;
    const int b = bh >> 4, head = bh & 15;
    const int tid = threadIdx.x;
    const int w = tid >> 6;
    const int lane = tid & 63;
    const int l31 = lane & 31, hi = lane >> 5;
    const int r7 = l31 & 7;
    const int pair = w >> 1, sub = w & 1;
    const int q0 = bq * 64;
    const int qg = q0 + sub * 32 + l31;
    const int rounds = (bq >> 1) + 1;
    const float c2 = 0.125f * 1.44269504088896340736f;  // scale * log2(e)
    const float THRraw = 44.3614195558f;                // 8 / c2

    // Q fragments (B-operand): Q[q][16kc + 8hi + 0..7]
    bf16x8 qf[4];
    {
        const u16* qp = Qb + (size_t)(b * SS + qg) * 1024 + head * 64 + hi * 8;
        #pragma unroll
        for (int kc = 0; kc < 4; ++kc)
            qf[kc] = __builtin_bit_cast(bf16x8, *reinterpret_cast<const u16x8*>(qp + kc * 16));
    }

    f32x16 acc0 = {}, acc1 = {};   // O^T partial: d rows (0..31 / 32..63), col = q
    float mrow = -3.0e38f, lrow = 0.f;

#define STAGE2(cur_, r_) do { \
    _Pragma("unroll") \
    for (int p_ = 0; p_ < 2; ++p_) { \
        int kt_ = 2 * (r_) + p_; \
        if (kt_ <= bq) { \
            int k0_ = kt_ * 64; \
            char* base_ = lds + (((cur_) << 1) | p_) * 16384; \
            _Pragma("unroll") \
            for (int c_ = 0; c_ < 2; ++c_) { \
                int i_ = tid + 256 * c_; int row_ = i_ >> 3; int sc_ = (i_ & 7) ^ (row_ & 7); \
                __builtin_amdgcn_global_load_lds( \
                    (const AS1 void*)(Kb + (size_t)(b * SS + k0_ + row_) * 1024 + head * 64 + sc_ * 8), \
                    (AS3 void*)((AS3 char*)(AS3 void*)base_ + c_ * 4096 + w * 1024), 16, 0, 0); \
                __builtin_amdgcn_global_load_lds( \
                    (const AS1 void*)(VtG + (size_t)(bh * 64 + row_) * 2048 + k0_ + sc_ * 8), \
                    (AS3 void*)((AS3 char*)(AS3 void*)base_ + 8192 + c_ * 4096 + w * 1024), 16, 0, 0); \
            } \
        } \
    } } while (0)

    int cur = 0;
    STAGE2(0, 0);
    __syncthreads();

    for (int r = 0; r < rounds; ++r) {
        if (r + 1 < rounds) STAGE2(cur ^ 1, r + 1);
        const int kt = 2 * r + pair;
        if (kt <= bq) {
            const char* Kb_ = lds + ((cur << 1) | pair) * 16384;
            const char* Vb_ = Kb_ + 8192;
            const int k0 = kt * 64;
            // S^T = K @ Q^T
            f32x16 s0 = {}, s1 = {};
            __builtin_amdgcn_s_setprio(1);
            #pragma unroll
            for (int kc = 0; kc < 4; ++kc) {
                bf16x8 kf0 = lds_frag(Kb_ + (l31) * 128 + ((2 * kc + hi) ^ r7) * 16);
                bf16x8 kf1 = lds_frag(Kb_ + (32 + l31) * 128 + ((2 * kc + hi) ^ r7) * 16);
                s0 = __builtin_amdgcn_mfma_f32_32x32x16_bf16(kf0, qf[kc], s0, 0, 0, 0);
                s1 = __builtin_amdgcn_mfma_f32_32x32x16_bf16(kf1, qf[kc], s1, 0, 0, 0);
            }
            __builtin_amdgcn_s_setprio(0);
            if (kt == bq) {   // diagonal tile: causal mask
                const int lim = qg - k0 - hi * 4;
                #pragma unroll
                for (int r2 = 0; r2 < 16; ++r2) {
                    const int ko = (r2 & 3) + 8 * (r2 >> 2);
                    s0[r2] = (ko > lim) ? -3.0e38f : s0[r2];
                    s1[r2] = (ko + 32 > lim) ? -3.0e38f : s1[r2];
                }
            }
            // tree max + cross-half exchange
            float a8[8];
            #pragma unroll
            for (int i = 0; i < 8; ++i)
                a8[i] = fmaxf(fmaxf(s0[2 * i], s0[2 * i + 1]), fmaxf(s1[2 * i], s1[2 * i + 1]));
            float tm = fmaxf(fmaxf(fmaxf(a8[0], a8[1]), fmaxf(a8[2], a8[3])),
                             fmaxf(fmaxf(a8[4], a8[5]), fmaxf(a8[6], a8[7])));
            tm = fmaxf(tm, __shfl_xor(tm, 32));
            // defer-max
            bool nofix = __all(tm <= mrow + THRraw);
            float scale = 1.f;
            if (!nofix) {
                float mnew = fmaxf(mrow, tm);
                scale = exp2f((mrow - mnew) * c2);
                mrow = mnew;
            }
            float mc = mrow * c2;
            #pragma unroll
            for (int r2 = 0; r2 < 16; ++r2) {
                s0[r2] = exp2f(__builtin_fmaf(s0[r2], c2, -mc));
                s1[r2] = exp2f(__builtin_fmaf(s1[r2], c2, -mc));
            }
            float c8[8];
            #pragma unroll
            for (int i = 0; i < 8; ++i)
                c8[i] = (s0[2 * i] + s0[2 * i + 1]) + (s1[2 * i] + s1[2 * i + 1]);
            float rsum = ((c8[0] + c8[1]) + (c8[2] + c8[3])) + ((c8[4] + c8[5]) + (c8[6] + c8[7]));
            rsum += __shfl_xor(rsum, 32);
            if (nofix) {
                lrow += rsum;
            } else {
                lrow = lrow * scale + rsum;
                #pragma unroll
                for (int r2 = 0; r2 < 16; ++r2) { acc0[r2] *= scale; acc1[r2] *= scale; }
            }
            // pack P to bf16 pairs
            u32 cg0[4][2], cg1[4][2];
            #pragma unroll
            for (int g = 0; g < 4; ++g) {
                #pragma unroll
                for (int w2 = 0; w2 < 2; ++w2) {
                    cg0[g][w2] = cvtpk_bf16(s0[4 * g + 2 * w2], s0[4 * g + 2 * w2 + 1]);
                    cg1[g][w2] = cvtpk_bf16(s1[4 * g + 2 * w2], s1[4 * g + 2 * w2 + 1]);
                }
            }
            // assemble P frags via shfl_xor(32): pa[ks] = P[q][16ks + 8hi + 0..7]
            bf16x8 pa[4];
            #pragma unroll
            for (int ks = 0; ks < 4; ++ks) {
                const int g0 = (2 * ks) & 3, g1 = g0 + 1;
                u32 a0, a1, b0, b1;
                if (ks < 2) { a0 = cg0[g0][0]; a1 = cg0[g0][1]; b0 = cg0[g1][0]; b1 = cg0[g1][1]; }
                else        { a0 = cg1[g0][0]; a1 = cg1[g0][1]; b0 = cg1[g1][0]; b1 = cg1[g1][1]; }
                u32 pa0 = (u32)__shfl_xor((int)a0, 32);
                u32 pa1 = (u32)__shfl_xor((int)a1, 32);
                u32 pb0 = (u32)__shfl_xor((int)b0, 32);
                u32 pb1 = (u32)__shfl_xor((int)b1, 32);
                u32x4 f;
                f.x = hi ? pb0 : a0;
                f.y = hi ? pb1 : a1;
                f.z = hi ? b0 : pa0;
                f.w = hi ? b1 : pa1;
                pa[ks] = __builtin_bit_cast(bf16x8, f);
            }
            // O^T += V^T @ P^T
            __builtin_amdgcn_s_setprio(1);
            #pragma unroll
            for (int ks = 0; ks < 4; ++ks) {
                bf16x8 vf0 = lds_frag(Vb_ + (l31) * 128 + ((2 * ks + hi) ^ r7) * 16);
                bf16x8 vf1 = lds_frag(Vb_ + (32 + l31) * 128 + ((2 * ks + hi) ^ r7) * 16);
                acc0 = __builtin_amdgcn_mfma_f32_32x32x16_bf16(vf0, pa[ks], acc0, 0, 0, 0);
                acc1 = __builtin_amdgcn_mfma_f32_32x32x16_bf16(vf1, pa[ks], acc1, 0, 0, 0);
            }
            __builtin_amdgcn_s_setprio(0);
        }
        __syncthreads();
        cur ^= 1;
    }
#undef STAGE2

    // write partials to LDS (aliases staging region; all compute done)
    float* part = (float*)lds;                    // [4][32][65]
    float* mls  = (float*)(lds + 33280);          // [4][2][32]
    #pragma unroll
    for (int r2 = 0; r2 < 16; ++r2) {
        const int d = (r2 & 3) + 8 * (r2 >> 2) + 4 * hi;
        part[(w * 32 + l31) * 65 + d] = acc0[r2];
        part[(w * 32 + l31) * 65 + d + 32] = acc1[r2];
    }
    if (hi == 0) {
        mls[(w * 2 + 0) * 32 + l31] = mrow;
        mls[(w * 2 + 1) * 32 + l31] = lrow;
    }
    __syncthreads();

    // combine 2 partials: thread -> q = tid>>2 (0..63), d-seg = (tid&3)*16
    {
        const int q = tid >> 2, ds0 = (tid & 3) * 16;
        const int s_ = q >> 5, qq = q & 31;
        const int wa_ = s_, wb_ = 2 + s_;
        float ma = mls[(wa_ * 2 + 0) * 32 + qq], la = mls[(wa_ * 2 + 1) * 32 + qq];
        float mb = mls[(wb_ * 2 + 0) * 32 + qq], lb = mls[(wb_ * 2 + 1) * 32 + qq];
        float mt = fmaxf(ma, mb);
        float wa = exp2f((ma - mt) * c2);
        float wb = exp2f((mb - mt) * c2);
        float lt = la * wa + lb * wb;
        float inv = 1.0f / lt;
        u16x8 ov0, ov1;
        #pragma unroll
        for (int i = 0; i < 8; ++i) {
            float v0 = part[(wa_ * 32 + qq) * 65 + ds0 + i] * wa +
                       part[(wb_ * 32 + qq) * 65 + ds0 + i] * wb;
            float v1 = part[(wa_ * 32 + qq) * 65 + ds0 + 8 + i] * wa +
                       part[(wb_ * 32 + qq) * 65 + ds0 + 8 + i] * wb;
            ov0[i] = f2bf(v0 * inv);
            ov1[i] = f2bf(v1 * inv);
        }
        u16* op = O + (size_t)(b * SS + q0 + q) * 1024 + head * 64 + ds0;
        *reinterpret_cast<u16x8*>(op) = ov0;
        *reinterpret_cast<u16x8*>(op + 8) = ov1;
    }
}

// ---------------- launch ----------------

extern "C" void kernel_launch(void* const* d_in, const int* in_sizes, int n_in,
                              void* d_out, int out_size, void* d_ws, size_t ws_size,
                              hipStream_t stream) {
    const float* x     = (const float*)d_in[0];
    const float* W_dq  = (const float*)d_in[1];
    const float* W_uq  = (const float*)d_in[2];
    const float* W_dkv = (const float*)d_in[3];
    const float* W_uk  = (const float*)d_in[4];
    const float* W_uv  = (const float*)d_in[5];
    const float* W_o   = (const float*)d_in[6];
    float* out = (float*)d_out;

    char* ws = (char*)d_ws;
    u16* xb      = (u16*)(ws);                          // 8 MB   [4096][1024]
    u16* c_qkv   = (u16*)(ws + (8u << 20));             // 4 MB   [4096][512]
    u16* Qb      = (u16*)(ws + (12u << 20));            // 8 MB   [4096][1024]
    u16* Kb      = (u16*)(ws + (20u << 20));            // 8 MB   [4096][1024] (K only)
    u16* Vt      = (u16*)(ws + (36u << 20));            // 8 MB   [2048][2048]
    u16* attno   = (u16*)(ws + (44u << 20));            // 8 MB   [4096][1024]
    u16* Wdqkv_t = (u16*)(ws + (52u << 20));            // 1 MB   [512][1024]
    u16* Wuq_t   = (u16*)(ws + (53u << 20));            // 0.5 MB [1024][256]
    u16* Wukv_t  = (u16*)(ws + (53u << 20) + (512u << 10)); // 1 MB [2048][256]
    u16* Wo_t    = (u16*)(ws + (55u << 20));            // 2 MB   [1024][1024]

    dim3 blk(256);
    prep<<<dim3(32, 32, 7), blk, 0, stream>>>(x, xb, W_dq, W_dkv, W_uq, W_uk, W_uv, W_o,
        Wdqkv_t, Wdqkv_t + 256 * 1024, Wuq_t, Wukv_t, Wukv_t + 1024 * 256, Wo_t);
    // c_qkv = x @ [W_dq | W_dkv]   [4096,512] K=1024, BM=64/BN=64 -> 512 blocks
    gemmT<64, 64, 1><<<dim3(8, 64), blk, 0, stream>>>(xb, DM, Wdqkv_t, DM, c_qkv, 512, DM);
    // Q | K | V(transposed) up-projection, K=256  (768 blocks)
    gemm_qkv<<<dim3(24, 32), blk, 0, stream>>>(c_qkv, Wuq_t, Wukv_t, Qb, Kb, Vt);
    // attention: 1024 blocks, pair-parity split, LPT order
    attn_mfma6<<<dim3(1024), blk, 0, stream>>>(Qb, Kb, Vt, attno);
    // out = attno @ W_o   [4096,1024] K=1024, BM=64/BN=128 -> 512 blocks, fp32 out
    gemmT<64, 128, 0><<<dim3(8, 64), blk, 0, stream>>>(attno, DM, Wo_t, DM, out, DM, DM);
}

// Round 13
// 105.811 us; speedup vs baseline: 1.6150x; 1.1222x over previous
//
#include <hip/hip_runtime.h>
#include <math.h>

#define AS3 __attribute__((address_space(3)))
#define AS1 __attribute__((address_space(1)))

typedef unsigned short u16;
typedef unsigned int u32;
typedef __bf16 bf16_t;
typedef bf16_t bf16x8 __attribute__((ext_vector_type(8)));
typedef float f32x4 __attribute__((ext_vector_type(4)));
typedef float f32x16 __attribute__((ext_vector_type(16)));
typedef unsigned short u16x4 __attribute__((ext_vector_type(4)));
typedef unsigned short u16x8 __attribute__((ext_vector_type(8)));
typedef unsigned int u32x4 __attribute__((ext_vector_type(4)));

#define NH 16
#define DK 64
#define DC 256
#define DM 1024
#define BB 2
#define SS 2048
#define TT (BB*SS)

__device__ __forceinline__ u16 f2bf(float f) {
    unsigned u = __builtin_bit_cast(unsigned, f);
    unsigned r = (u + 0x7FFFu + ((u >> 16) & 1u)) >> 16;
    return (u16)r;
}

__device__ __forceinline__ u32 cvtpk_bf16(float a, float b) {
    u32 d;
    asm("v_cvt_pk_bf16_f32 %0, %1, %2" : "=v"(d) : "v"(a), "v"(b));
    return d;
}

__device__ __forceinline__ bf16x8 lds_frag(const char* p) {
    return __builtin_bit_cast(bf16x8, *reinterpret_cast<const u16x8*>(p));
}

// ---------------- fused prep: x->bf16 (z=6) + 6 weight transposes (z=0..5) ----------------
__global__ __launch_bounds__(256) void prep(const float* __restrict__ x, u16* __restrict__ xb,
                                            const float* w0, const float* w1, const float* w2,
                                            const float* w3, const float* w4, const float* w5,
                                            u16* d0, u16* d1, u16* d2, u16* d3, u16* d4, u16* d5) {
    __shared__ float t[32][33];
    const int z = blockIdx.z;
    if (z == 6) {
        int blk = blockIdx.y * 32 + blockIdx.x;
        int i = (blk * 256 + threadIdx.x) * 16;
        float4 v0 = *reinterpret_cast<const float4*>(x + i);
        float4 v1 = *reinterpret_cast<const float4*>(x + i + 4);
        float4 v2 = *reinterpret_cast<const float4*>(x + i + 8);
        float4 v3 = *reinterpret_cast<const float4*>(x + i + 12);
        u16x8 o0, o1;
        o0[0] = f2bf(v0.x); o0[1] = f2bf(v0.y); o0[2] = f2bf(v0.z); o0[3] = f2bf(v0.w);
        o0[4] = f2bf(v1.x); o0[5] = f2bf(v1.y); o0[6] = f2bf(v1.z); o0[7] = f2bf(v1.w);
        o1[0] = f2bf(v2.x); o1[1] = f2bf(v2.y); o1[2] = f2bf(v2.z); o1[3] = f2bf(v2.w);
        o1[4] = f2bf(v3.x); o1[5] = f2bf(v3.y); o1[6] = f2bf(v3.z); o1[7] = f2bf(v3.w);
        *reinterpret_cast<u16x8*>(xb + i) = o0;
        *reinterpret_cast<u16x8*>(xb + i + 8) = o1;
        return;
    }
    const float* src; u16* dst; int R, C, opitch;
    switch (z) {
        case 0:  src = w0; dst = d0; R = 1024; C = 256;  opitch = 1024; break;
        case 1:  src = w1; dst = d1; R = 1024; C = 256;  opitch = 1024; break;
        case 2:  src = w2; dst = d2; R = 256;  C = 1024; opitch = 256;  break;
        case 3:  src = w3; dst = d3; R = 256;  C = 1024; opitch = 256;  break;
        case 4:  src = w4; dst = d4; R = 256;  C = 1024; opitch = 256;  break;
        default: src = w5; dst = d5; R = 1024; C = 1024; opitch = 1024; break;
    }
    int c0 = blockIdx.x * 32, r0 = blockIdx.y * 32;
    if (c0 >= C || r0 >= R) return;
    int tx = threadIdx.x & 31, ty = threadIdx.x >> 5;
    #pragma unroll
    for (int p = 0; p < 4; ++p)
        t[ty + 8 * p][tx] = src[(r0 + ty + 8 * p) * C + c0 + tx];
    __syncthreads();
    #pragma unroll
    for (int p = 0; p < 4; ++p)
        dst[(c0 + ty + 8 * p) * opitch + r0 + tx] = f2bf(t[tx][ty + 8 * p]);
}

// ---------------- MFMA GEMM body: C[BM x BN] tile at (bm, bn) ----------------
// 4 waves as 2x2; wave covers (BM/2)x(BN/2). MF=BM/32, NF=BN/32 frags.
// OUT_MODE: 0 = f32 normal, 1 = bf16 normal, 2 = bf16 transposed into Vt
template <int BM, int BN, int OUT_MODE>
__device__ __forceinline__ void gemm_body(const u16* __restrict__ A, int lda,
                                          const u16* __restrict__ Bt, int ldb,
                                          void* __restrict__ C, int ldc, int K,
                                          int bm, int bn, u16* As, u16* Bs) {
    constexpr int MF = BM / 32;
    constexpr int NF = BN / 32;
    constexpr int AI = BM / 64;
    constexpr int BI = BN / 64;
    const int tid = threadIdx.x;
    const int lane = tid & 63;
    const int w = tid >> 6;
    const int wr = w >> 1, wc = w & 1;
    const int l15 = lane & 15, l4 = lane >> 4;

    f32x4 acc[MF][NF] = {};

    for (int k0 = 0; k0 < K; k0 += 32) {
        #pragma unroll
        for (int i = 0; i < AI; ++i) {
            int db = i * 4096 + tid * 16;
            int row = db >> 6;
            int kc = (db & 63) >> 1;
            __builtin_amdgcn_global_load_lds(
                (const AS1 void*)(A + (bm + row) * lda + k0 + kc),
                (AS3 void*)((AS3 char*)(AS3 void*)As + i * 4096 + w * 1024), 16, 0, 0);
        }
        #pragma unroll
        for (int i = 0; i < BI; ++i) {
            int db = i * 4096 + tid * 16;
            int row = db >> 6;
            int kc = (db & 63) >> 1;
            __builtin_amdgcn_global_load_lds(
                (const AS1 void*)(Bt + (bn + row) * ldb + k0 + kc),
                (AS3 void*)((AS3 char*)(AS3 void*)Bs + i * 4096 + w * 1024), 16, 0, 0);
        }
        __syncthreads();
        bf16x8 a[MF], b[NF];
        #pragma unroll
        for (int m = 0; m < MF; ++m)
            a[m] = __builtin_bit_cast(bf16x8,
                *reinterpret_cast<const u16x8*>(&As[(wr * (BM / 2) + m * 16 + l15) * 32 + l4 * 8]));
        #pragma unroll
        for (int n = 0; n < NF; ++n)
            b[n] = __builtin_bit_cast(bf16x8,
                *reinterpret_cast<const u16x8*>(&Bs[(wc * (BN / 2) + n * 16 + l15) * 32 + l4 * 8]));
        #pragma unroll
        for (int m = 0; m < MF; ++m)
            #pragma unroll
            for (int n = 0; n < NF; ++n)
                acc[m][n] = __builtin_amdgcn_mfma_f32_16x16x32_bf16(a[m], b[n], acc[m][n], 0, 0, 0);
        __syncthreads();
    }
    if (OUT_MODE == 2) {
        // transposed store: per (m,n), j=0..3 are consecutive s positions of one Vt row
        #pragma unroll
        for (int m = 0; m < MF; ++m) {
            int row = bm + wr * (BM / 2) + m * 16 + l4 * 4;   // = b*2048 + s, s%4==0
            int vrow_base = (row >> 11) << 10;
            int scol = row & 2047;
            #pragma unroll
            for (int n = 0; n < NF; ++n) {
                int col = bn + wc * (BN / 2) + n * 16 + l15;   // v-dim
                u16x4 ov;
                ov[0] = f2bf(acc[m][n][0]); ov[1] = f2bf(acc[m][n][1]);
                ov[2] = f2bf(acc[m][n][2]); ov[3] = f2bf(acc[m][n][3]);
                *reinterpret_cast<u16x4*>((u16*)C + (size_t)(vrow_base + col) * 2048 + scol) = ov;
            }
        }
    } else {
        #pragma unroll
        for (int m = 0; m < MF; ++m) {
            int row = bm + wr * (BM / 2) + m * 16 + l4 * 4;
            #pragma unroll
            for (int j = 0; j < 4; ++j) {
                #pragma unroll
                for (int n = 0; n < NF; ++n) {
                    int col = bn + wc * (BN / 2) + n * 16 + l15;
                    if (OUT_MODE == 1)
                        ((u16*)C)[(row + j) * ldc + col] = f2bf(acc[m][n][j]);
                    else
                        ((float*)C)[(row + j) * ldc + col] = acc[m][n][j];
                }
            }
        }
    }
}

template <int BM, int BN, int OUT_MODE>
__global__ __launch_bounds__(256) void gemmT(const u16* __restrict__ A, int lda,
                                             const u16* __restrict__ Bt, int ldb,
                                             void* __restrict__ C, int ldc, int K) {
    __shared__ u16 As[BM * 32];
    __shared__ u16 Bs[BN * 32];
    gemm_body<BM, BN, OUT_MODE>(A, lda, Bt, ldb, C, ldc, K,
                                blockIdx.y * BM, blockIdx.x * BN, As, Bs);
}

// fused Q + K + V up-projection, K=256:
//   bx 0..7  -> Q tile   (Qb [4096][1024])
//   bx 8..15 -> K tile   (Kb [4096][1024], K-only)
//   bx 16..23-> V tile   (written transposed into Vt [2048][2048])
__global__ __launch_bounds__(256) void gemm_qkv(const u16* __restrict__ c_qkv,
                                                const u16* __restrict__ Wuq_t,
                                                const u16* __restrict__ Wukv_t,
                                                u16* __restrict__ Qb, u16* __restrict__ Kb,
                                                u16* __restrict__ Vt) {
    __shared__ u16 As[128 * 32];
    __shared__ u16 Bs[128 * 32];
    const int bx = blockIdx.x;
    if (bx < 8) {
        gemm_body<128, 128, 1>(c_qkv, 512, Wuq_t, 256, Qb, 1024, 256,
                               blockIdx.y * 128, bx * 128, As, Bs);
    } else if (bx < 16) {
        gemm_body<128, 128, 1>(c_qkv + 256, 512, Wukv_t, 256, Kb, 1024, 256,
                               blockIdx.y * 128, (bx - 8) * 128, As, Bs);
    } else {
        gemm_body<128, 128, 2>(c_qkv + 256, 512, Wukv_t + 1024 * 256, 256, Vt, 0, 256,
                               blockIdx.y * 128, (bx - 16) * 128, As, Bs);
    }
}

// ---------------- MFMA causal flash attention v10: single-buffer, 4 blocks/CU ----------------
// Block = (bq 64 q-rows, bh). Waves {0,1} even key-tiles, {2,3} odd; wave owns
// 32 q-rows. K/V LDS-staged per tile (2 slots, single-buffered); TLP across the
// 4 resident blocks/CU hides the staging latency. 2-partial LDS merge at end.
__global__ __launch_bounds__(256, 4) void attn_mfma6(const u16* __restrict__ Qb,
                                                     const u16* __restrict__ Kb,
                                                     const u16* __restrict__ VtG,
                                                     u16* __restrict__ O) {
    __shared__ char lds[34304];   // 2 slots x (8KB K + 8KB V); combine aliases 34304 B
    const int bid = blockIdx.x;
    const int bq = 31 - (bid >> 5);      // big jobs dispatch first
    const int bh = bid & 31;
    const int b = bh >> 4, head = bh & 15;
    const int tid = threadIdx.x;
    const int w = tid >> 6;
    const int lane = tid & 63;
    const int l31 = lane & 31, hi = lane >> 5;
    const int r7 = l31 & 7;
    const int pair = w >> 1, sub = w & 1;
    const int q0 = bq * 64;
    const int qg = q0 + sub * 32 + l31;
    const int rounds = (bq >> 1) + 1;
    const float c2 = 0.125f * 1.44269504088896340736f;  // scale * log2(e)
    const float THRraw = 44.3614195558f;                // 8 / c2

    // Q fragments (B-operand): Q[q][16kc + 8hi + 0..7]
    bf16x8 qf[4];
    {
        const u16* qp = Qb + (size_t)(b * SS + qg) * 1024 + head * 64 + hi * 8;
        #pragma unroll
        for (int kc = 0; kc < 4; ++kc)
            qf[kc] = __builtin_bit_cast(bf16x8, *reinterpret_cast<const u16x8*>(qp + kc * 16));
    }

    f32x16 acc0 = {}, acc1 = {};   // O^T partial: d rows (0..31 / 32..63), col = q
    float mrow = -3.0e38f, lrow = 0.f;

#define STAGE2(r_) do { \
    _Pragma("unroll") \
    for (int p_ = 0; p_ < 2; ++p_) { \
        int kt_ = 2 * (r_) + p_; \
        if (kt_ <= bq) { \
            int k0_ = kt_ * 64; \
            char* base_ = lds + p_ * 16384; \
            _Pragma("unroll") \
            for (int c_ = 0; c_ < 2; ++c_) { \
                int i_ = tid + 256 * c_; int row_ = i_ >> 3; int sc_ = (i_ & 7) ^ (row_ & 7); \
                __builtin_amdgcn_global_load_lds( \
                    (const AS1 void*)(Kb + (size_t)(b * SS + k0_ + row_) * 1024 + head * 64 + sc_ * 8), \
                    (AS3 void*)((AS3 char*)(AS3 void*)base_ + c_ * 4096 + w * 1024), 16, 0, 0); \
                __builtin_amdgcn_global_load_lds( \
                    (const AS1 void*)(VtG + (size_t)(bh * 64 + row_) * 2048 + k0_ + sc_ * 8), \
                    (AS3 void*)((AS3 char*)(AS3 void*)base_ + 8192 + c_ * 4096 + w * 1024), 16, 0, 0); \
            } \
        } \
    } } while (0)

    for (int r = 0; r < rounds; ++r) {
        STAGE2(r);
        __syncthreads();   // staging complete (implies vmcnt drain)
        const int kt = 2 * r + pair;
        if (kt <= bq) {
            const char* Kb_ = lds + pair * 16384;
            const char* Vb_ = Kb_ + 8192;
            const int k0 = kt * 64;
            // S^T = K @ Q^T
            f32x16 s0 = {}, s1 = {};
            __builtin_amdgcn_s_setprio(1);
            #pragma unroll
            for (int kc = 0; kc < 4; ++kc) {
                bf16x8 kf0 = lds_frag(Kb_ + (l31) * 128 + ((2 * kc + hi) ^ r7) * 16);
                bf16x8 kf1 = lds_frag(Kb_ + (32 + l31) * 128 + ((2 * kc + hi) ^ r7) * 16);
                s0 = __builtin_amdgcn_mfma_f32_32x32x16_bf16(kf0, qf[kc], s0, 0, 0, 0);
                s1 = __builtin_amdgcn_mfma_f32_32x32x16_bf16(kf1, qf[kc], s1, 0, 0, 0);
            }
            __builtin_amdgcn_s_setprio(0);
            if (kt == bq) {   // diagonal tile: causal mask
                const int lim = qg - k0 - hi * 4;
                #pragma unroll
                for (int r2 = 0; r2 < 16; ++r2) {
                    const int ko = (r2 & 3) + 8 * (r2 >> 2);
                    s0[r2] = (ko > lim) ? -3.0e38f : s0[r2];
                    s1[r2] = (ko + 32 > lim) ? -3.0e38f : s1[r2];
                }
            }
            // tree max + cross-half exchange
            float a8[8];
            #pragma unroll
            for (int i = 0; i < 8; ++i)
                a8[i] = fmaxf(fmaxf(s0[2 * i], s0[2 * i + 1]), fmaxf(s1[2 * i], s1[2 * i + 1]));
            float tm = fmaxf(fmaxf(fmaxf(a8[0], a8[1]), fmaxf(a8[2], a8[3])),
                             fmaxf(fmaxf(a8[4], a8[5]), fmaxf(a8[6], a8[7])));
            tm = fmaxf(tm, __shfl_xor(tm, 32));
            // defer-max
            bool nofix = __all(tm <= mrow + THRraw);
            float scale = 1.f;
            if (!nofix) {
                float mnew = fmaxf(mrow, tm);
                scale = exp2f((mrow - mnew) * c2);
                mrow = mnew;
            }
            float mc = mrow * c2;
            #pragma unroll
            for (int r2 = 0; r2 < 16; ++r2) {
                s0[r2] = exp2f(__builtin_fmaf(s0[r2], c2, -mc));
                s1[r2] = exp2f(__builtin_fmaf(s1[r2], c2, -mc));
            }
            float c8[8];
            #pragma unroll
            for (int i = 0; i < 8; ++i)
                c8[i] = (s0[2 * i] + s0[2 * i + 1]) + (s1[2 * i] + s1[2 * i + 1]);
            float rsum = ((c8[0] + c8[1]) + (c8[2] + c8[3])) + ((c8[4] + c8[5]) + (c8[6] + c8[7]));
            rsum += __shfl_xor(rsum, 32);
            if (nofix) {
                lrow += rsum;
            } else {
                lrow = lrow * scale + rsum;
                #pragma unroll
                for (int r2 = 0; r2 < 16; ++r2) { acc0[r2] *= scale; acc1[r2] *= scale; }
            }
            // pack P to bf16 pairs
            u32 cg0[4][2], cg1[4][2];
            #pragma unroll
            for (int g = 0; g < 4; ++g) {
                #pragma unroll
                for (int w2 = 0; w2 < 2; ++w2) {
                    cg0[g][w2] = cvtpk_bf16(s0[4 * g + 2 * w2], s0[4 * g + 2 * w2 + 1]);
                    cg1[g][w2] = cvtpk_bf16(s1[4 * g + 2 * w2], s1[4 * g + 2 * w2 + 1]);
                }
            }
            // assemble P frags via shfl_xor(32): pa[ks] = P[q][16ks + 8hi + 0..7]
            bf16x8 pa[4];
            #pragma unroll
            for (int ks = 0; ks < 4; ++ks) {
                const int g0 = (2 * ks) & 3, g1 = g0 + 1;
                u32 a0, a1, b0, b1;
                if (ks < 2) { a0 = cg0[g0][0]; a1 = cg0[g0][1]; b0 = cg0[g1][0]; b1 = cg0[g1][1]; }
                else        { a0 = cg1[g0][0]; a1 = cg1[g0][1]; b0 = cg1[g1][0]; b1 = cg1[g1][1]; }
                u32 pa0 = (u32)__shfl_xor((int)a0, 32);
                u32 pa1 = (u32)__shfl_xor((int)a1, 32);
                u32 pb0 = (u32)__shfl_xor((int)b0, 32);
                u32 pb1 = (u32)__shfl_xor((int)b1, 32);
                u32x4 f;
                f.x = hi ? pb0 : a0;
                f.y = hi ? pb1 : a1;
                f.z = hi ? b0 : pa0;
                f.w = hi ? b1 : pa1;
                pa[ks] = __builtin_bit_cast(bf16x8, f);
            }
            // O^T += V^T @ P^T
            __builtin_amdgcn_s_setprio(1);
            #pragma unroll
            for (int ks = 0; ks < 4; ++ks) {
                bf16x8 vf0 = lds_frag(Vb_ + (l31) * 128 + ((2 * ks + hi) ^ r7) * 16);
                bf16x8 vf1 = lds_frag(Vb_ + (32 + l31) * 128 + ((2 * ks + hi) ^ r7) * 16);
                acc0 = __builtin_amdgcn_mfma_f32_32x32x16_bf16(vf0, pa[ks], acc0, 0, 0, 0);
                acc1 = __builtin_amdgcn_mfma_f32_32x32x16_bf16(vf1, pa[ks], acc1, 0, 0, 0);
            }
            __builtin_amdgcn_s_setprio(0);
        }
        __syncthreads();   // all reads done; safe to restage next round
    }
#undef STAGE2

    // write partials to LDS (aliases staging region; all compute done)
    float* part = (float*)lds;                    // [4][32][65]
    float* mls  = (float*)(lds + 33280);          // [4][2][32]
    #pragma unroll
    for (int r2 = 0; r2 < 16; ++r2) {
        const int d = (r2 & 3) + 8 * (r2 >> 2) + 4 * hi;
        part[(w * 32 + l31) * 65 + d] = acc0[r2];
        part[(w * 32 + l31) * 65 + d + 32] = acc1[r2];
    }
    if (hi == 0) {
        mls[(w * 2 + 0) * 32 + l31] = mrow;
        mls[(w * 2 + 1) * 32 + l31] = lrow;
    }
    __syncthreads();

    // combine 2 partials: thread -> q = tid>>2 (0..63), d-seg = (tid&3)*16
    {
        const int q = tid >> 2, ds0 = (tid & 3) * 16;
        const int s_ = q >> 5, qq = q & 31;
        const int wa_ = s_, wb_ = 2 + s_;
        float ma = mls[(wa_ * 2 + 0) * 32 + qq], la = mls[(wa_ * 2 + 1) * 32 + qq];
        float mb = mls[(wb_ * 2 + 0) * 32 + qq], lb = mls[(wb_ * 2 + 1) * 32 + qq];
        float mt = fmaxf(ma, mb);
        float wa = exp2f((ma - mt) * c2);
        float wb = exp2f((mb - mt) * c2);
        float lt = la * wa + lb * wb;
        float inv = 1.0f / lt;
        u16x8 ov0, ov1;
        #pragma unroll
        for (int i = 0; i < 8; ++i) {
            float v0 = part[(wa_ * 32 + qq) * 65 + ds0 + i] * wa +
                       part[(wb_ * 32 + qq) * 65 + ds0 + i] * wb;
            float v1 = part[(wa_ * 32 + qq) * 65 + ds0 + 8 + i] * wa +
                       part[(wb_ * 32 + qq) * 65 + ds0 + 8 + i] * wb;
            ov0[i] = f2bf(v0 * inv);
            ov1[i] = f2bf(v1 * inv);
        }
        u16* op = O + (size_t)(b * SS + q0 + q) * 1024 + head * 64 + ds0;
        *reinterpret_cast<u16x8*>(op) = ov0;
        *reinterpret_cast<u16x8*>(op + 8) = ov1;
    }
}

// ---------------- launch ----------------

extern "C" void kernel_launch(void* const* d_in, const int* in_sizes, int n_in,
                              void* d_out, int out_size, void* d_ws, size_t ws_size,
                              hipStream_t stream) {
    const float* x     = (const float*)d_in[0];
    const float* W_dq  = (const float*)d_in[1];
    const float* W_uq  = (const float*)d_in[2];
    const float* W_dkv = (const float*)d_in[3];
    const float* W_uk  = (const float*)d_in[4];
    const float* W_uv  = (const float*)d_in[5];
    const float* W_o   = (const float*)d_in[6];
    float* out = (float*)d_out;

    char* ws = (char*)d_ws;
    u16* xb      = (u16*)(ws);                          // 8 MB   [4096][1024]
    u16* c_qkv   = (u16*)(ws + (8u << 20));             // 4 MB   [4096][512]
    u16* Qb      = (u16*)(ws + (12u << 20));            // 8 MB   [4096][1024]
    u16* Kb      = (u16*)(ws + (20u << 20));            // 8 MB   [4096][1024] (K only)
    u16* Vt      = (u16*)(ws + (36u << 20));            // 8 MB   [2048][2048]
    u16* attno   = (u16*)(ws + (44u << 20));            // 8 MB   [4096][1024]
    u16* Wdqkv_t = (u16*)(ws + (52u << 20));            // 1 MB   [512][1024]
    u16* Wuq_t   = (u16*)(ws + (53u << 20));            // 0.5 MB [1024][256]
    u16* Wukv_t  = (u16*)(ws + (53u << 20) + (512u << 10)); // 1 MB [2048][256]
    u16* Wo_t    = (u16*)(ws + (55u << 20));            // 2 MB   [1024][1024]

    dim3 blk(256);
    prep<<<dim3(32, 32, 7), blk, 0, stream>>>(x, xb, W_dq, W_dkv, W_uq, W_uk, W_uv, W_o,
        Wdqkv_t, Wdqkv_t + 256 * 1024, Wuq_t, Wukv_t, Wukv_t + 1024 * 256, Wo_t);
    // c_qkv = x @ [W_dq | W_dkv]   [4096,512] K=1024, BM=64/BN=64 -> 512 blocks
    gemmT<64, 64, 1><<<dim3(8, 64), blk, 0, stream>>>(xb, DM, Wdqkv_t, DM, c_qkv, 512, DM);
    // Q | K | V(transposed) up-projection, K=256  (768 blocks)
    gemm_qkv<<<dim3(24, 32), blk, 0, stream>>>(c_qkv, Wuq_t, Wukv_t, Qb, Kb, Vt);
    // attention: 1024 blocks, pair-parity split, single-buffered staging
    attn_mfma6<<<dim3(1024), blk, 0, stream>>>(Qb, Kb, Vt, attno);
    // out = attno @ W_o   [4096,1024] K=1024, BM=64/BN=128 -> 512 blocks, fp32 out
    gemmT<64, 128, 0><<<dim3(8, 64), blk, 0, stream>>>(attno, DM, Wo_t, DM, out, DM, DM);
}

// Round 14
// 104.502 us; speedup vs baseline: 1.6353x; 1.0125x over previous
//
#include <hip/hip_runtime.h>
#include <math.h>

#define AS3 __attribute__((address_space(3)))
#define AS1 __attribute__((address_space(1)))

typedef unsigned short u16;
typedef unsigned int u32;
typedef __bf16 bf16_t;
typedef bf16_t bf16x8 __attribute__((ext_vector_type(8)));
typedef float f32x4 __attribute__((ext_vector_type(4)));
typedef float f32x16 __attribute__((ext_vector_type(16)));
typedef unsigned short u16x4 __attribute__((ext_vector_type(4)));
typedef unsigned short u16x8 __attribute__((ext_vector_type(8)));
typedef unsigned int u32x4 __attribute__((ext_vector_type(4)));

#define NH 16
#define DK 64
#define DC 256
#define DM 1024
#define BB 2
#define SS 2048
#define TT (BB*SS)

__device__ __forceinline__ u16 f2bf(float f) {
    unsigned u = __builtin_bit_cast(unsigned, f);
    unsigned r = (u + 0x7FFFu + ((u >> 16) & 1u)) >> 16;
    return (u16)r;
}

__device__ __forceinline__ u32 cvtpk_bf16(float a, float b) {
    u32 d;
    asm("v_cvt_pk_bf16_f32 %0, %1, %2" : "=v"(d) : "v"(a), "v"(b));
    return d;
}

__device__ __forceinline__ bf16x8 lds_frag(const char* p) {
    return __builtin_bit_cast(bf16x8, *reinterpret_cast<const u16x8*>(p));
}

// ---------------- prep: 6 weight transposes (fp32 [K][N] -> bf16 [N][K]) ----------------
__global__ __launch_bounds__(256) void prep(const float* w0, const float* w1, const float* w2,
                                            const float* w3, const float* w4, const float* w5,
                                            u16* d0, u16* d1, u16* d2, u16* d3, u16* d4, u16* d5) {
    __shared__ float t[32][33];
    const int z = blockIdx.z;
    const float* src; u16* dst; int R, C, opitch;
    switch (z) {
        case 0:  src = w0; dst = d0; R = 1024; C = 256;  opitch = 1024; break;
        case 1:  src = w1; dst = d1; R = 1024; C = 256;  opitch = 1024; break;
        case 2:  src = w2; dst = d2; R = 256;  C = 1024; opitch = 256;  break;
        case 3:  src = w3; dst = d3; R = 256;  C = 1024; opitch = 256;  break;
        case 4:  src = w4; dst = d4; R = 256;  C = 1024; opitch = 256;  break;
        default: src = w5; dst = d5; R = 1024; C = 1024; opitch = 1024; break;
    }
    int c0 = blockIdx.x * 32, r0 = blockIdx.y * 32;
    if (c0 >= C || r0 >= R) return;
    int tx = threadIdx.x & 31, ty = threadIdx.x >> 5;
    #pragma unroll
    for (int p = 0; p < 4; ++p)
        t[ty + 8 * p][tx] = src[(r0 + ty + 8 * p) * C + c0 + tx];
    __syncthreads();
    #pragma unroll
    for (int p = 0; p < 4; ++p)
        dst[(c0 + ty + 8 * p) * opitch + r0 + tx] = f2bf(t[tx][ty + 8 * p]);
}

// ---------------- gemm_dqkv: c_qkv[4096,512] = x(f32) @ Wdqkv_t^T, BK=64 ----------------
// BM=64, BN=64. A staged from fp32 with in-register bf16 conversion.
__global__ __launch_bounds__(256) void gemm_dqkv(const float* __restrict__ X,
                                                 const u16* __restrict__ Bt,
                                                 u16* __restrict__ Cc) {
    __shared__ u16 As[2][64 * 32];
    __shared__ u16 Bs[2][64 * 32];
    const int tid = threadIdx.x;
    const int lane = tid & 63;
    const int w = tid >> 6;
    const int wr = w >> 1, wc = w & 1;
    const int bm = blockIdx.y * 64, bn = blockIdx.x * 64;
    const int l15 = lane & 15, l4 = lane >> 4;
    const int arow = tid >> 2, akc = (tid & 3) * 8;
    const int brow = tid >> 2, bkc = (tid & 3) * 8;   // same decomposition for B dest

    f32x4 acc[2][2] = {};

    for (int k0 = 0; k0 < 1024; k0 += 64) {
        #pragma unroll
        for (int h = 0; h < 2; ++h) {
            const float* xp = X + (size_t)(bm + arow) * 1024 + k0 + h * 32 + akc;
            float4 v0 = *reinterpret_cast<const float4*>(xp);
            float4 v1 = *reinterpret_cast<const float4*>(xp + 4);
            u32x4 o;
            o.x = cvtpk_bf16(v0.x, v0.y);
            o.y = cvtpk_bf16(v0.z, v0.w);
            o.z = cvtpk_bf16(v1.x, v1.y);
            o.w = cvtpk_bf16(v1.z, v1.w);
            *reinterpret_cast<u32x4*>(&As[h][arow * 32 + akc]) = o;
        }
        #pragma unroll
        for (int h = 0; h < 2; ++h) {
            __builtin_amdgcn_global_load_lds(
                (const AS1 void*)(Bt + (size_t)(bn + brow) * 1024 + k0 + h * 32 + bkc),
                (AS3 void*)((AS3 char*)(AS3 void*)&Bs[h][0] + w * 1024), 16, 0, 0);
        }
        __syncthreads();
        #pragma unroll
        for (int h = 0; h < 2; ++h) {
            bf16x8 a[2], b[2];
            #pragma unroll
            for (int m = 0; m < 2; ++m)
                a[m] = __builtin_bit_cast(bf16x8,
                    *reinterpret_cast<const u16x8*>(&As[h][(wr * 32 + m * 16 + l15) * 32 + l4 * 8]));
            #pragma unroll
            for (int n = 0; n < 2; ++n)
                b[n] = __builtin_bit_cast(bf16x8,
                    *reinterpret_cast<const u16x8*>(&Bs[h][(wc * 32 + n * 16 + l15) * 32 + l4 * 8]));
            #pragma unroll
            for (int m = 0; m < 2; ++m)
                #pragma unroll
                for (int n = 0; n < 2; ++n)
                    acc[m][n] = __builtin_amdgcn_mfma_f32_16x16x32_bf16(a[m], b[n], acc[m][n], 0, 0, 0);
        }
        __syncthreads();
    }
    #pragma unroll
    for (int m = 0; m < 2; ++m) {
        int row = bm + wr * 32 + m * 16 + l4 * 4;
        #pragma unroll
        for (int j = 0; j < 4; ++j)
            #pragma unroll
            for (int n = 0; n < 2; ++n) {
                int col = bn + wc * 32 + n * 16 + l15;
                Cc[(size_t)(row + j) * 512 + col] = f2bf(acc[m][n][j]);
            }
    }
}

// ---------------- gemm_out: out[4096,1024](f32) = attno @ Wo_t^T, BK=64 ----------------
// BM=64, BN=128.
__global__ __launch_bounds__(256) void gemm_out(const u16* __restrict__ A,
                                                const u16* __restrict__ Bt,
                                                float* __restrict__ C) {
    __shared__ u16 As[2][64 * 32];
    __shared__ u16 Bs[2][128 * 32];
    const int tid = threadIdx.x;
    const int lane = tid & 63;
    const int w = tid >> 6;
    const int wr = w >> 1, wc = w & 1;
    const int bm = blockIdx.y * 64, bn = blockIdx.x * 128;
    const int l15 = lane & 15, l4 = lane >> 4;

    f32x4 acc[2][4] = {};

    for (int k0 = 0; k0 < 1024; k0 += 64) {
        #pragma unroll
        for (int h = 0; h < 2; ++h) {
            {   // A: 64x32 = 4 KB
                int db = tid * 16;
                int row = db >> 6;
                int kc = (db & 63) >> 1;
                __builtin_amdgcn_global_load_lds(
                    (const AS1 void*)(A + (size_t)(bm + row) * 1024 + k0 + h * 32 + kc),
                    (AS3 void*)((AS3 char*)(AS3 void*)&As[h][0] + w * 1024), 16, 0, 0);
            }
            #pragma unroll
            for (int i = 0; i < 2; ++i) {   // B: 128x32 = 8 KB
                int db = i * 4096 + tid * 16;
                int row = db >> 6;
                int kc = (db & 63) >> 1;
                __builtin_amdgcn_global_load_lds(
                    (const AS1 void*)(Bt + (size_t)(bn + row) * 1024 + k0 + h * 32 + kc),
                    (AS3 void*)((AS3 char*)(AS3 void*)&Bs[h][0] + i * 4096 + w * 1024), 16, 0, 0);
            }
        }
        __syncthreads();
        #pragma unroll
        for (int h = 0; h < 2; ++h) {
            bf16x8 a[2], b[4];
            #pragma unroll
            for (int m = 0; m < 2; ++m)
                a[m] = __builtin_bit_cast(bf16x8,
                    *reinterpret_cast<const u16x8*>(&As[h][(wr * 32 + m * 16 + l15) * 32 + l4 * 8]));
            #pragma unroll
            for (int n = 0; n < 4; ++n)
                b[n] = __builtin_bit_cast(bf16x8,
                    *reinterpret_cast<const u16x8*>(&Bs[h][(wc * 64 + n * 16 + l15) * 32 + l4 * 8]));
            #pragma unroll
            for (int m = 0; m < 2; ++m)
                #pragma unroll
                for (int n = 0; n < 4; ++n)
                    acc[m][n] = __builtin_amdgcn_mfma_f32_16x16x32_bf16(a[m], b[n], acc[m][n], 0, 0, 0);
        }
        __syncthreads();
    }
    #pragma unroll
    for (int m = 0; m < 2; ++m) {
        int row = bm + wr * 32 + m * 16 + l4 * 4;
        #pragma unroll
        for (int j = 0; j < 4; ++j)
            #pragma unroll
            for (int n = 0; n < 4; ++n) {
                int col = bn + wc * 64 + n * 16 + l15;
                C[(size_t)(row + j) * 1024 + col] = acc[m][n][j];
            }
    }
}

// ---------------- MFMA GEMM body (128x128, BK=32) for the fused QKV projection ----------------
// OUT_MODE: 1 = bf16 normal, 2 = bf16 transposed into Vt
template <int OUT_MODE>
__device__ __forceinline__ void gemm_body128(const u16* __restrict__ A, int lda,
                                             const u16* __restrict__ Bt, int ldb,
                                             void* __restrict__ C, int ldc, int K,
                                             int bm, int bn, u16* As, u16* Bs) {
    const int tid = threadIdx.x;
    const int lane = tid & 63;
    const int w = tid >> 6;
    const int wr = w >> 1, wc = w & 1;
    const int l15 = lane & 15, l4 = lane >> 4;

    f32x4 acc[4][4] = {};

    for (int k0 = 0; k0 < K; k0 += 32) {
        #pragma unroll
        for (int i = 0; i < 2; ++i) {
            int db = i * 4096 + tid * 16;
            int row = db >> 6;
            int kc = (db & 63) >> 1;
            __builtin_amdgcn_global_load_lds(
                (const AS1 void*)(A + (size_t)(bm + row) * lda + k0 + kc),
                (AS3 void*)((AS3 char*)(AS3 void*)As + i * 4096 + w * 1024), 16, 0, 0);
            __builtin_amdgcn_global_load_lds(
                (const AS1 void*)(Bt + (size_t)(bn + row) * ldb + k0 + kc),
                (AS3 void*)((AS3 char*)(AS3 void*)Bs + i * 4096 + w * 1024), 16, 0, 0);
        }
        __syncthreads();
        bf16x8 a[4], b[4];
        #pragma unroll
        for (int m = 0; m < 4; ++m)
            a[m] = __builtin_bit_cast(bf16x8,
                *reinterpret_cast<const u16x8*>(&As[(wr * 64 + m * 16 + l15) * 32 + l4 * 8]));
        #pragma unroll
        for (int n = 0; n < 4; ++n)
            b[n] = __builtin_bit_cast(bf16x8,
                *reinterpret_cast<const u16x8*>(&Bs[(wc * 64 + n * 16 + l15) * 32 + l4 * 8]));
        #pragma unroll
        for (int m = 0; m < 4; ++m)
            #pragma unroll
            for (int n = 0; n < 4; ++n)
                acc[m][n] = __builtin_amdgcn_mfma_f32_16x16x32_bf16(a[m], b[n], acc[m][n], 0, 0, 0);
        __syncthreads();
    }
    if (OUT_MODE == 2) {
        #pragma unroll
        for (int m = 0; m < 4; ++m) {
            int row = bm + wr * 64 + m * 16 + l4 * 4;   // = b*2048 + s, s%4==0
            int vrow_base = (row >> 11) << 10;
            int scol = row & 2047;
            #pragma unroll
            for (int n = 0; n < 4; ++n) {
                int col = bn + wc * 64 + n * 16 + l15;   // v-dim
                u16x4 ov;
                ov[0] = f2bf(acc[m][n][0]); ov[1] = f2bf(acc[m][n][1]);
                ov[2] = f2bf(acc[m][n][2]); ov[3] = f2bf(acc[m][n][3]);
                *reinterpret_cast<u16x4*>((u16*)C + (size_t)(vrow_base + col) * 2048 + scol) = ov;
            }
        }
    } else {
        #pragma unroll
        for (int m = 0; m < 4; ++m) {
            int row = bm + wr * 64 + m * 16 + l4 * 4;
            #pragma unroll
            for (int j = 0; j < 4; ++j)
                #pragma unroll
                for (int n = 0; n < 4; ++n) {
                    int col = bn + wc * 64 + n * 16 + l15;
                    ((u16*)C)[(size_t)(row + j) * ldc + col] = f2bf(acc[m][n][j]);
                }
        }
    }
}

// fused Q + K + V up-projection, K=256:
//   bx 0..7  -> Q tile (Qb [4096][1024]); 8..15 -> K tile (Kb [4096][1024]);
//   16..23   -> V tile written transposed into Vt [2048][2048]
__global__ __launch_bounds__(256) void gemm_qkv(const u16* __restrict__ c_qkv,
                                                const u16* __restrict__ Wuq_t,
                                                const u16* __restrict__ Wukv_t,
                                                u16* __restrict__ Qb, u16* __restrict__ Kb,
                                                u16* __restrict__ Vt) {
    __shared__ u16 As[128 * 32];
    __shared__ u16 Bs[128 * 32];
    const int bx = blockIdx.x;
    if (bx < 8) {
        gemm_body128<1>(c_qkv, 512, Wuq_t, 256, Qb, 1024, 256,
                        blockIdx.y * 128, bx * 128, As, Bs);
    } else if (bx < 16) {
        gemm_body128<1>(c_qkv + 256, 512, Wukv_t, 256, Kb, 1024, 256,
                        blockIdx.y * 128, (bx - 8) * 128, As, Bs);
    } else {
        gemm_body128<2>(c_qkv + 256, 512, Wukv_t + 1024 * 256, 256, Vt, 0, 256,
                        blockIdx.y * 128, (bx - 16) * 128, As, Bs);
    }
}

// ---------------- MFMA causal flash attention (R13-verified, unchanged) ----------------
__global__ __launch_bounds__(256, 4) void attn_mfma6(const u16* __restrict__ Qb,
                                                     const u16* __restrict__ Kb,
                                                     const u16* __restrict__ VtG,
                                                     u16* __restrict__ O) {
    __shared__ char lds[34304];   // 2 slots x (8KB K + 8KB V); combine aliases 34304 B
    const int bid = blockIdx.x;
    const int bq = 31 - (bid >> 5);      // big jobs dispatch first
    const int bh = bid & 31;
    const int b = bh >> 4, head = bh & 15;
    const int tid = threadIdx.x;
    const int w = tid >> 6;
    const int lane = tid & 63;
    const int l31 = lane & 31, hi = lane >> 5;
    const int r7 = l31 & 7;
    const int pair = w >> 1, sub = w & 1;
    const int q0 = bq * 64;
    const int qg = q0 + sub * 32 + l31;
    const int rounds = (bq >> 1) + 1;
    const float c2 = 0.125f * 1.44269504088896340736f;  // scale * log2(e)
    const float THRraw = 44.3614195558f;                // 8 / c2

    // Q fragments (B-operand): Q[q][16kc + 8hi + 0..7]
    bf16x8 qf[4];
    {
        const u16* qp = Qb + (size_t)(b * SS + qg) * 1024 + head * 64 + hi * 8;
        #pragma unroll
        for (int kc = 0; kc < 4; ++kc)
            qf[kc] = __builtin_bit_cast(bf16x8, *reinterpret_cast<const u16x8*>(qp + kc * 16));
    }

    f32x16 acc0 = {}, acc1 = {};   // O^T partial: d rows (0..31 / 32..63), col = q
    float mrow = -3.0e38f, lrow = 0.f;

#define STAGE2(r_) do { \
    _Pragma("unroll") \
    for (int p_ = 0; p_ < 2; ++p_) { \
        int kt_ = 2 * (r_) + p_; \
        if (kt_ <= bq) { \
            int k0_ = kt_ * 64; \
            char* base_ = lds + p_ * 16384; \
            _Pragma("unroll") \
            for (int c_ = 0; c_ < 2; ++c_) { \
                int i_ = tid + 256 * c_; int row_ = i_ >> 3; int sc_ = (i_ & 7) ^ (row_ & 7); \
                __builtin_amdgcn_global_load_lds( \
                    (const AS1 void*)(Kb + (size_t)(b * SS + k0_ + row_) * 1024 + head * 64 + sc_ * 8), \
                    (AS3 void*)((AS3 char*)(AS3 void*)base_ + c_ * 4096 + w * 1024), 16, 0, 0); \
                __builtin_amdgcn_global_load_lds( \
                    (const AS1 void*)(VtG + (size_t)(bh * 64 + row_) * 2048 + k0_ + sc_ * 8), \
                    (AS3 void*)((AS3 char*)(AS3 void*)base_ + 8192 + c_ * 4096 + w * 1024), 16, 0, 0); \
            } \
        } \
    } } while (0)

    for (int r = 0; r < rounds; ++r) {
        STAGE2(r);
        __syncthreads();   // staging complete (implies vmcnt drain)
        const int kt = 2 * r + pair;
        if (kt <= bq) {
            const char* Kb_ = lds + pair * 16384;
            const char* Vb_ = Kb_ + 8192;
            const int k0 = kt * 64;
            // S^T = K @ Q^T
            f32x16 s0 = {}, s1 = {};
            __builtin_amdgcn_s_setprio(1);
            #pragma unroll
            for (int kc = 0; kc < 4; ++kc) {
                bf16x8 kf0 = lds_frag(Kb_ + (l31) * 128 + ((2 * kc + hi) ^ r7) * 16);
                bf16x8 kf1 = lds_frag(Kb_ + (32 + l31) * 128 + ((2 * kc + hi) ^ r7) * 16);
                s0 = __builtin_amdgcn_mfma_f32_32x32x16_bf16(kf0, qf[kc], s0, 0, 0, 0);
                s1 = __builtin_amdgcn_mfma_f32_32x32x16_bf16(kf1, qf[kc], s1, 0, 0, 0);
            }
            __builtin_amdgcn_s_setprio(0);
            if (kt == bq) {   // diagonal tile: causal mask
                const int lim = qg - k0 - hi * 4;
                #pragma unroll
                for (int r2 = 0; r2 < 16; ++r2) {
                    const int ko = (r2 & 3) + 8 * (r2 >> 2);
                    s0[r2] = (ko > lim) ? -3.0e38f : s0[r2];
                    s1[r2] = (ko + 32 > lim) ? -3.0e38f : s1[r2];
                }
            }
            // tree max + cross-half exchange
            float a8[8];
            #pragma unroll
            for (int i = 0; i < 8; ++i)
                a8[i] = fmaxf(fmaxf(s0[2 * i], s0[2 * i + 1]), fmaxf(s1[2 * i], s1[2 * i + 1]));
            float tm = fmaxf(fmaxf(fmaxf(a8[0], a8[1]), fmaxf(a8[2], a8[3])),
                             fmaxf(fmaxf(a8[4], a8[5]), fmaxf(a8[6], a8[7])));
            tm = fmaxf(tm, __shfl_xor(tm, 32));
            // defer-max
            bool nofix = __all(tm <= mrow + THRraw);
            float scale = 1.f;
            if (!nofix) {
                float mnew = fmaxf(mrow, tm);
                scale = exp2f((mrow - mnew) * c2);
                mrow = mnew;
            }
            float mc = mrow * c2;
            #pragma unroll
            for (int r2 = 0; r2 < 16; ++r2) {
                s0[r2] = exp2f(__builtin_fmaf(s0[r2], c2, -mc));
                s1[r2] = exp2f(__builtin_fmaf(s1[r2], c2, -mc));
            }
            float c8[8];
            #pragma unroll
            for (int i = 0; i < 8; ++i)
                c8[i] = (s0[2 * i] + s0[2 * i + 1]) + (s1[2 * i] + s1[2 * i + 1]);
            float rsum = ((c8[0] + c8[1]) + (c8[2] + c8[3])) + ((c8[4] + c8[5]) + (c8[6] + c8[7]));
            rsum += __shfl_xor(rsum, 32);
            if (nofix) {
                lrow += rsum;
            } else {
                lrow = lrow * scale + rsum;
                #pragma unroll
                for (int r2 = 0; r2 < 16; ++r2) { acc0[r2] *= scale; acc1[r2] *= scale; }
            }
            // pack P to bf16 pairs
            u32 cg0[4][2], cg1[4][2];
            #pragma unroll
            for (int g = 0; g < 4; ++g) {
                #pragma unroll
                for (int w2 = 0; w2 < 2; ++w2) {
                    cg0[g][w2] = cvtpk_bf16(s0[4 * g + 2 * w2], s0[4 * g + 2 * w2 + 1]);
                    cg1[g][w2] = cvtpk_bf16(s1[4 * g + 2 * w2], s1[4 * g + 2 * w2 + 1]);
                }
            }
            // assemble P frags via shfl_xor(32): pa[ks] = P[q][16ks + 8hi + 0..7]
            bf16x8 pa[4];
            #pragma unroll
            for (int ks = 0; ks < 4; ++ks) {
                const int g0 = (2 * ks) & 3, g1 = g0 + 1;
                u32 a0, a1, b0, b1;
                if (ks < 2) { a0 = cg0[g0][0]; a1 = cg0[g0][1]; b0 = cg0[g1][0]; b1 = cg0[g1][1]; }
                else        { a0 = cg1[g0][0]; a1 = cg1[g0][1]; b0 = cg1[g1][0]; b1 = cg1[g1][1]; }
                u32 pa0 = (u32)__shfl_xor((int)a0, 32);
                u32 pa1 = (u32)__shfl_xor((int)a1, 32);
                u32 pb0 = (u32)__shfl_xor((int)b0, 32);
                u32 pb1 = (u32)__shfl_xor((int)b1, 32);
                u32x4 f;
                f.x = hi ? pb0 : a0;
                f.y = hi ? pb1 : a1;
                f.z = hi ? b0 : pa0;
                f.w = hi ? b1 : pa1;
                pa[ks] = __builtin_bit_cast(bf16x8, f);
            }
            // O^T += V^T @ P^T
            __builtin_amdgcn_s_setprio(1);
            #pragma unroll
            for (int ks = 0; ks < 4; ++ks) {
                bf16x8 vf0 = lds_frag(Vb_ + (l31) * 128 + ((2 * ks + hi) ^ r7) * 16);
                bf16x8 vf1 = lds_frag(Vb_ + (32 + l31) * 128 + ((2 * ks + hi) ^ r7) * 16);
                acc0 = __builtin_amdgcn_mfma_f32_32x32x16_bf16(vf0, pa[ks], acc0, 0, 0, 0);
                acc1 = __builtin_amdgcn_mfma_f32_32x32x16_bf16(vf1, pa[ks], acc1, 0, 0, 0);
            }
            __builtin_amdgcn_s_setprio(0);
        }
        __syncthreads();   // all reads done; safe to restage next round
    }
#undef STAGE2

    // write partials to LDS (aliases staging region; all compute done)
    float* part = (float*)lds;                    // [4][32][65]
    float* mls  = (float*)(lds + 33280);          // [4][2][32]
    #pragma unroll
    for (int r2 = 0; r2 < 16; ++r2) {
        const int d = (r2 & 3) + 8 * (r2 >> 2) + 4 * hi;
        part[(w * 32 + l31) * 65 + d] = acc0[r2];
        part[(w * 32 + l31) * 65 + d + 32] = acc1[r2];
    }
    if (hi == 0) {
        mls[(w * 2 + 0) * 32 + l31] = mrow;
        mls[(w * 2 + 1) * 32 + l31] = lrow;
    }
    __syncthreads();

    // combine 2 partials: thread -> q = tid>>2 (0..63), d-seg = (tid&3)*16
    {
        const int q = tid >> 2, ds0 = (tid & 3) * 16;
        const int s_ = q >> 5, qq = q & 31;
        const int wa_ = s_, wb_ = 2 + s_;
        float ma = mls[(wa_ * 2 + 0) * 32 + qq], la = mls[(wa_ * 2 + 1) * 32 + qq];
        float mb = mls[(wb_ * 2 + 0) * 32 + qq], lb = mls[(wb_ * 2 + 1) * 32 + qq];
        float mt = fmaxf(ma, mb);
        float wa = exp2f((ma - mt) * c2);
        float wb = exp2f((mb - mt) * c2);
        float lt = la * wa + lb * wb;
        float inv = 1.0f / lt;
        u16x8 ov0, ov1;
        #pragma unroll
        for (int i = 0; i < 8; ++i) {
            float v0 = part[(wa_ * 32 + qq) * 65 + ds0 + i] * wa +
                       part[(wb_ * 32 + qq) * 65 + ds0 + i] * wb;
            float v1 = part[(wa_ * 32 + qq) * 65 + ds0 + 8 + i] * wa +
                       part[(wb_ * 32 + qq) * 65 + ds0 + 8 + i] * wb;
            ov0[i] = f2bf(v0 * inv);
            ov1[i] = f2bf(v1 * inv);
        }
        u16* op = O + (size_t)(b * SS + q0 + q) * 1024 + head * 64 + ds0;
        *reinterpret_cast<u16x8*>(op) = ov0;
        *reinterpret_cast<u16x8*>(op + 8) = ov1;
    }
}

// ---------------- launch ----------------

extern "C" void kernel_launch(void* const* d_in, const int* in_sizes, int n_in,
                              void* d_out, int out_size, void* d_ws, size_t ws_size,
                              hipStream_t stream) {
    const float* x     = (const float*)d_in[0];
    const float* W_dq  = (const float*)d_in[1];
    const float* W_uq  = (const float*)d_in[2];
    const float* W_dkv = (const float*)d_in[3];
    const float* W_uk  = (const float*)d_in[4];
    const float* W_uv  = (const float*)d_in[5];
    const float* W_o   = (const float*)d_in[6];
    float* out = (float*)d_out;

    char* ws = (char*)d_ws;
    u16* c_qkv   = (u16*)(ws + (8u << 20));             // 4 MB   [4096][512]
    u16* Qb      = (u16*)(ws + (12u << 20));            // 8 MB   [4096][1024]
    u16* Kb      = (u16*)(ws + (20u << 20));            // 8 MB   [4096][1024] (K only)
    u16* Vt      = (u16*)(ws + (36u << 20));            // 8 MB   [2048][2048]
    u16* attno   = (u16*)(ws + (44u << 20));            // 8 MB   [4096][1024]
    u16* Wdqkv_t = (u16*)(ws + (52u << 20));            // 1 MB   [512][1024]
    u16* Wuq_t   = (u16*)(ws + (53u << 20));            // 0.5 MB [1024][256]
    u16* Wukv_t  = (u16*)(ws + (53u << 20) + (512u << 10)); // 1 MB [2048][256]
    u16* Wo_t    = (u16*)(ws + (55u << 20));            // 2 MB   [1024][1024]

    dim3 blk(256);
    // weight transposes only (x handled in gemm_dqkv)
    prep<<<dim3(32, 32, 6), blk, 0, stream>>>(W_dq, W_dkv, W_uq, W_uk, W_uv, W_o,
        Wdqkv_t, Wdqkv_t + 256 * 1024, Wuq_t, Wukv_t, Wukv_t + 1024 * 256, Wo_t);
    // c_qkv = x(f32) @ [W_dq | W_dkv]   BK=64, fused fp32->bf16 A staging
    gemm_dqkv<<<dim3(8, 64), blk, 0, stream>>>(x, Wdqkv_t, c_qkv);
    // Q | K | V(transposed) up-projection, K=256  (768 blocks)
    gemm_qkv<<<dim3(24, 32), blk, 0, stream>>>(c_qkv, Wuq_t, Wukv_t, Qb, Kb, Vt);
    // attention: 1024 blocks, pair-parity split, single-buffered staging
    attn_mfma6<<<dim3(1024), blk, 0, stream>>>(Qb, Kb, Vt, attno);
    // out = attno @ W_o   BK=64, BM=64/BN=128 -> 512 blocks, fp32 out
    gemm_out<<<dim3(8, 64), blk, 0, stream>>>(attno, Wo_t, out);
}

// Round 15
// 103.716 us; speedup vs baseline: 1.6477x; 1.0076x over previous
//
#include <hip/hip_runtime.h>
#include <math.h>

#define AS3 __attribute__((address_space(3)))
#define AS1 __attribute__((address_space(1)))

typedef unsigned short u16;
typedef unsigned int u32;
typedef __bf16 bf16_t;
typedef bf16_t bf16x8 __attribute__((ext_vector_type(8)));
typedef float f32x4 __attribute__((ext_vector_type(4)));
typedef float f32x16 __attribute__((ext_vector_type(16)));
typedef unsigned short u16x4 __attribute__((ext_vector_type(4)));
typedef unsigned short u16x8 __attribute__((ext_vector_type(8)));
typedef unsigned int u32x4 __attribute__((ext_vector_type(4)));

#define NH 16
#define DK 64
#define DC 256
#define DM 1024
#define BB 2
#define SS 2048
#define TT (BB*SS)

__device__ __forceinline__ u16 f2bf(float f) {
    unsigned u = __builtin_bit_cast(unsigned, f);
    unsigned r = (u + 0x7FFFu + ((u >> 16) & 1u)) >> 16;
    return (u16)r;
}

__device__ __forceinline__ float bf2f(u16 h) {
    u32 u = ((u32)h) << 16;
    return __builtin_bit_cast(float, u);
}

__device__ __forceinline__ u32 cvtpk_bf16(float a, float b) {
    u32 d;
    asm("v_cvt_pk_bf16_f32 %0, %1, %2" : "=v"(d) : "v"(a), "v"(b));
    return d;
}

__device__ __forceinline__ bf16x8 lds_frag(const char* p) {
    return __builtin_bit_cast(bf16x8, *reinterpret_cast<const u16x8*>(p));
}

// ---------------- prep: 6 weight transposes (fp32 [K][N] -> bf16 [N][K]) ----------------
__global__ __launch_bounds__(256) void prep(const float* w0, const float* w1, const float* w2,
                                            const float* w3, const float* w4, const float* w5,
                                            u16* d0, u16* d1, u16* d2, u16* d3, u16* d4, u16* d5) {
    __shared__ float t[32][33];
    const int z = blockIdx.z;
    const float* src; u16* dst; int R, C, opitch;
    switch (z) {
        case 0:  src = w0; dst = d0; R = 1024; C = 256;  opitch = 1024; break;
        case 1:  src = w1; dst = d1; R = 1024; C = 256;  opitch = 1024; break;
        case 2:  src = w2; dst = d2; R = 256;  C = 1024; opitch = 256;  break;
        case 3:  src = w3; dst = d3; R = 256;  C = 1024; opitch = 256;  break;
        case 4:  src = w4; dst = d4; R = 256;  C = 1024; opitch = 256;  break;
        default: src = w5; dst = d5; R = 1024; C = 1024; opitch = 1024; break;
    }
    int c0 = blockIdx.x * 32, r0 = blockIdx.y * 32;
    if (c0 >= C || r0 >= R) return;
    int tx = threadIdx.x & 31, ty = threadIdx.x >> 5;
    #pragma unroll
    for (int p = 0; p < 4; ++p)
        t[ty + 8 * p][tx] = src[(r0 + ty + 8 * p) * C + c0 + tx];
    __syncthreads();
    #pragma unroll
    for (int p = 0; p < 4; ++p)
        dst[(c0 + ty + 8 * p) * opitch + r0 + tx] = f2bf(t[tx][ty + 8 * p]);
}

// ---------------- gemm_dqkv: c_qkv[4096,512] = x(f32) @ Wdqkv_t^T, BK=64 ----------------
__global__ __launch_bounds__(256) void gemm_dqkv(const float* __restrict__ X,
                                                 const u16* __restrict__ Bt,
                                                 u16* __restrict__ Cc) {
    __shared__ u16 As[2][64 * 32];
    __shared__ u16 Bs[2][64 * 32];
    const int tid = threadIdx.x;
    const int lane = tid & 63;
    const int w = tid >> 6;
    const int wr = w >> 1, wc = w & 1;
    const int bm = blockIdx.y * 64, bn = blockIdx.x * 64;
    const int l15 = lane & 15, l4 = lane >> 4;
    const int arow = tid >> 2, akc = (tid & 3) * 8;
    const int brow = tid >> 2, bkc = (tid & 3) * 8;

    f32x4 acc[2][2] = {};

    for (int k0 = 0; k0 < 1024; k0 += 64) {
        #pragma unroll
        for (int h = 0; h < 2; ++h) {
            const float* xp = X + (size_t)(bm + arow) * 1024 + k0 + h * 32 + akc;
            float4 v0 = *reinterpret_cast<const float4*>(xp);
            float4 v1 = *reinterpret_cast<const float4*>(xp + 4);
            u32x4 o;
            o.x = cvtpk_bf16(v0.x, v0.y);
            o.y = cvtpk_bf16(v0.z, v0.w);
            o.z = cvtpk_bf16(v1.x, v1.y);
            o.w = cvtpk_bf16(v1.z, v1.w);
            *reinterpret_cast<u32x4*>(&As[h][arow * 32 + akc]) = o;
        }
        #pragma unroll
        for (int h = 0; h < 2; ++h) {
            __builtin_amdgcn_global_load_lds(
                (const AS1 void*)(Bt + (size_t)(bn + brow) * 1024 + k0 + h * 32 + bkc),
                (AS3 void*)((AS3 char*)(AS3 void*)&Bs[h][0] + w * 1024), 16, 0, 0);
        }
        __syncthreads();
        #pragma unroll
        for (int h = 0; h < 2; ++h) {
            bf16x8 a[2], b[2];
            #pragma unroll
            for (int m = 0; m < 2; ++m)
                a[m] = __builtin_bit_cast(bf16x8,
                    *reinterpret_cast<const u16x8*>(&As[h][(wr * 32 + m * 16 + l15) * 32 + l4 * 8]));
            #pragma unroll
            for (int n = 0; n < 2; ++n)
                b[n] = __builtin_bit_cast(bf16x8,
                    *reinterpret_cast<const u16x8*>(&Bs[h][(wc * 32 + n * 16 + l15) * 32 + l4 * 8]));
            #pragma unroll
            for (int m = 0; m < 2; ++m)
                #pragma unroll
                for (int n = 0; n < 2; ++n)
                    acc[m][n] = __builtin_amdgcn_mfma_f32_16x16x32_bf16(a[m], b[n], acc[m][n], 0, 0, 0);
        }
        __syncthreads();
    }
    #pragma unroll
    for (int m = 0; m < 2; ++m) {
        int row = bm + wr * 32 + m * 16 + l4 * 4;
        #pragma unroll
        for (int j = 0; j < 4; ++j)
            #pragma unroll
            for (int n = 0; n < 2; ++n) {
                int col = bn + wc * 32 + n * 16 + l15;
                Cc[(size_t)(row + j) * 512 + col] = f2bf(acc[m][n][j]);
            }
    }
}

// ---------------- gemm_out: out[4096,1024](f32) = attno @ Wo_t^T, BK=64 ----------------
__global__ __launch_bounds__(256) void gemm_out(const u16* __restrict__ A,
                                                const u16* __restrict__ Bt,
                                                float* __restrict__ C) {
    __shared__ u16 As[2][64 * 32];
    __shared__ u16 Bs[2][128 * 32];
    const int tid = threadIdx.x;
    const int lane = tid & 63;
    const int w = tid >> 6;
    const int wr = w >> 1, wc = w & 1;
    const int bm = blockIdx.y * 64, bn = blockIdx.x * 128;
    const int l15 = lane & 15, l4 = lane >> 4;

    f32x4 acc[2][4] = {};

    for (int k0 = 0; k0 < 1024; k0 += 64) {
        #pragma unroll
        for (int h = 0; h < 2; ++h) {
            {
                int db = tid * 16;
                int row = db >> 6;
                int kc = (db & 63) >> 1;
                __builtin_amdgcn_global_load_lds(
                    (const AS1 void*)(A + (size_t)(bm + row) * 1024 + k0 + h * 32 + kc),
                    (AS3 void*)((AS3 char*)(AS3 void*)&As[h][0] + w * 1024), 16, 0, 0);
            }
            #pragma unroll
            for (int i = 0; i < 2; ++i) {
                int db = i * 4096 + tid * 16;
                int row = db >> 6;
                int kc = (db & 63) >> 1;
                __builtin_amdgcn_global_load_lds(
                    (const AS1 void*)(Bt + (size_t)(bn + row) * 1024 + k0 + h * 32 + kc),
                    (AS3 void*)((AS3 char*)(AS3 void*)&Bs[h][0] + i * 4096 + w * 1024), 16, 0, 0);
            }
        }
        __syncthreads();
        #pragma unroll
        for (int h = 0; h < 2; ++h) {
            bf16x8 a[2], b[4];
            #pragma unroll
            for (int m = 0; m < 2; ++m)
                a[m] = __builtin_bit_cast(bf16x8,
                    *reinterpret_cast<const u16x8*>(&As[h][(wr * 32 + m * 16 + l15) * 32 + l4 * 8]));
            #pragma unroll
            for (int n = 0; n < 4; ++n)
                b[n] = __builtin_bit_cast(bf16x8,
                    *reinterpret_cast<const u16x8*>(&Bs[h][(wc * 64 + n * 16 + l15) * 32 + l4 * 8]));
            #pragma unroll
            for (int m = 0; m < 2; ++m)
                #pragma unroll
                for (int n = 0; n < 4; ++n)
                    acc[m][n] = __builtin_amdgcn_mfma_f32_16x16x32_bf16(a[m], b[n], acc[m][n], 0, 0, 0);
        }
        __syncthreads();
    }
    #pragma unroll
    for (int m = 0; m < 2; ++m) {
        int row = bm + wr * 32 + m * 16 + l4 * 4;
        #pragma unroll
        for (int j = 0; j < 4; ++j)
            #pragma unroll
            for (int n = 0; n < 4; ++n) {
                int col = bn + wc * 64 + n * 16 + l15;
                C[(size_t)(row + j) * 1024 + col] = acc[m][n][j];
            }
    }
}

// ---------------- MFMA GEMM body (128x128, BK=32) for the fused QKV projection ----------------
template <int OUT_MODE>
__device__ __forceinline__ void gemm_body128(const u16* __restrict__ A, int lda,
                                             const u16* __restrict__ Bt, int ldb,
                                             void* __restrict__ C, int ldc, int K,
                                             int bm, int bn, u16* As, u16* Bs) {
    const int tid = threadIdx.x;
    const int lane = tid & 63;
    const int w = tid >> 6;
    const int wr = w >> 1, wc = w & 1;
    const int l15 = lane & 15, l4 = lane >> 4;

    f32x4 acc[4][4] = {};

    for (int k0 = 0; k0 < K; k0 += 32) {
        #pragma unroll
        for (int i = 0; i < 2; ++i) {
            int db = i * 4096 + tid * 16;
            int row = db >> 6;
            int kc = (db & 63) >> 1;
            __builtin_amdgcn_global_load_lds(
                (const AS1 void*)(A + (size_t)(bm + row) * lda + k0 + kc),
                (AS3 void*)((AS3 char*)(AS3 void*)As + i * 4096 + w * 1024), 16, 0, 0);
            __builtin_amdgcn_global_load_lds(
                (const AS1 void*)(Bt + (size_t)(bn + row) * ldb + k0 + kc),
                (AS3 void*)((AS3 char*)(AS3 void*)Bs + i * 4096 + w * 1024), 16, 0, 0);
        }
        __syncthreads();
        bf16x8 a[4], b[4];
        #pragma unroll
        for (int m = 0; m < 4; ++m)
            a[m] = __builtin_bit_cast(bf16x8,
                *reinterpret_cast<const u16x8*>(&As[(wr * 64 + m * 16 + l15) * 32 + l4 * 8]));
        #pragma unroll
        for (int n = 0; n < 4; ++n)
            b[n] = __builtin_bit_cast(bf16x8,
                *reinterpret_cast<const u16x8*>(&Bs[(wc * 64 + n * 16 + l15) * 32 + l4 * 8]));
        #pragma unroll
        for (int m = 0; m < 4; ++m)
            #pragma unroll
            for (int n = 0; n < 4; ++n)
                acc[m][n] = __builtin_amdgcn_mfma_f32_16x16x32_bf16(a[m], b[n], acc[m][n], 0, 0, 0);
        __syncthreads();
    }
    if (OUT_MODE == 2) {
        #pragma unroll
        for (int m = 0; m < 4; ++m) {
            int row = bm + wr * 64 + m * 16 + l4 * 4;   // = b*2048 + s, s%4==0
            int vrow_base = (row >> 11) << 10;
            int scol = row & 2047;
            #pragma unroll
            for (int n = 0; n < 4; ++n) {
                int col = bn + wc * 64 + n * 16 + l15;   // v-dim
                u16x4 ov;
                ov[0] = f2bf(acc[m][n][0]); ov[1] = f2bf(acc[m][n][1]);
                ov[2] = f2bf(acc[m][n][2]); ov[3] = f2bf(acc[m][n][3]);
                *reinterpret_cast<u16x4*>((u16*)C + (size_t)(vrow_base + col) * 2048 + scol) = ov;
            }
        }
    } else {
        #pragma unroll
        for (int m = 0; m < 4; ++m) {
            int row = bm + wr * 64 + m * 16 + l4 * 4;
            #pragma unroll
            for (int j = 0; j < 4; ++j)
                #pragma unroll
                for (int n = 0; n < 4; ++n) {
                    int col = bn + wc * 64 + n * 16 + l15;
                    ((u16*)C)[(size_t)(row + j) * ldc + col] = f2bf(acc[m][n][j]);
                }
        }
    }
}

// fused Q + K + V up-projection, K=256
__global__ __launch_bounds__(256) void gemm_qkv(const u16* __restrict__ c_qkv,
                                                const u16* __restrict__ Wuq_t,
                                                const u16* __restrict__ Wukv_t,
                                                u16* __restrict__ Qb, u16* __restrict__ Kb,
                                                u16* __restrict__ Vt) {
    __shared__ u16 As[128 * 32];
    __shared__ u16 Bs[128 * 32];
    const int bx = blockIdx.x;
    if (bx < 8) {
        gemm_body128<1>(c_qkv, 512, Wuq_t, 256, Qb, 1024, 256,
                        blockIdx.y * 128, bx * 128, As, Bs);
    } else if (bx < 16) {
        gemm_body128<1>(c_qkv + 256, 512, Wukv_t, 256, Kb, 1024, 256,
                        blockIdx.y * 128, (bx - 8) * 128, As, Bs);
    } else {
        gemm_body128<2>(c_qkv + 256, 512, Wukv_t + 1024 * 256, 256, Vt, 0, 256,
                        blockIdx.y * 128, (bx - 16) * 128, As, Bs);
    }
}

// ---------------- MFMA causal flash attention v11: LDS=32KB -> 5 blocks/CU ----------------
// Identical compute to R13/R14; combine partials stored as bf16 ([4][32][72] u16,
// 16B-aligned pitch) + fp32 m/l so total LDS = staging 32768 B exactly.
__global__ __launch_bounds__(256, 4) void attn_mfma6(const u16* __restrict__ Qb,
                                                     const u16* __restrict__ Kb,
                                                     const u16* __restrict__ VtG,
                                                     u16* __restrict__ O) {
    __shared__ char lds[32768];   // 2 slots x (8KB K + 8KB V); combine aliases 19.5 KB
    const int bid = blockIdx.x;
    const int bq = 31 - (bid >> 5);      // big jobs dispatch first
    const int bh = bid & 31;
    const int b = bh >> 4, head = bh & 15;
    const int tid = threadIdx.x;
    const int w = tid >> 6;
    const int lane = tid & 63;
    const int l31 = lane & 31, hi = lane >> 5;
    const int r7 = l31 & 7;
    const int pair = w >> 1, sub = w & 1;
    const int q0 = bq * 64;
    const int qg = q0 + sub * 32 + l31;
    const int rounds = (bq >> 1) + 1;
    const float c2 = 0.125f * 1.44269504088896340736f;  // scale * log2(e)
    const float THRraw = 44.3614195558f;                // 8 / c2

    // Q fragments (B-operand): Q[q][16kc + 8hi + 0..7]
    bf16x8 qf[4];
    {
        const u16* qp = Qb + (size_t)(b * SS + qg) * 1024 + head * 64 + hi * 8;
        #pragma unroll
        for (int kc = 0; kc < 4; ++kc)
            qf[kc] = __builtin_bit_cast(bf16x8, *reinterpret_cast<const u16x8*>(qp + kc * 16));
    }

    f32x16 acc0 = {}, acc1 = {};   // O^T partial: d rows (0..31 / 32..63), col = q
    float mrow = -3.0e38f, lrow = 0.f;

#define STAGE2(r_) do { \
    _Pragma("unroll") \
    for (int p_ = 0; p_ < 2; ++p_) { \
        int kt_ = 2 * (r_) + p_; \
        if (kt_ <= bq) { \
            int k0_ = kt_ * 64; \
            char* base_ = lds + p_ * 16384; \
            _Pragma("unroll") \
            for (int c_ = 0; c_ < 2; ++c_) { \
                int i_ = tid + 256 * c_; int row_ = i_ >> 3; int sc_ = (i_ & 7) ^ (row_ & 7); \
                __builtin_amdgcn_global_load_lds( \
                    (const AS1 void*)(Kb + (size_t)(b * SS + k0_ + row_) * 1024 + head * 64 + sc_ * 8), \
                    (AS3 void*)((AS3 char*)(AS3 void*)base_ + c_ * 4096 + w * 1024), 16, 0, 0); \
                __builtin_amdgcn_global_load_lds( \
                    (const AS1 void*)(VtG + (size_t)(bh * 64 + row_) * 2048 + k0_ + sc_ * 8), \
                    (AS3 void*)((AS3 char*)(AS3 void*)base_ + 8192 + c_ * 4096 + w * 1024), 16, 0, 0); \
            } \
        } \
    } } while (0)

    for (int r = 0; r < rounds; ++r) {
        STAGE2(r);
        __syncthreads();   // staging complete (implies vmcnt drain)
        const int kt = 2 * r + pair;
        if (kt <= bq) {
            const char* Kb_ = lds + pair * 16384;
            const char* Vb_ = Kb_ + 8192;
            const int k0 = kt * 64;
            // S^T = K @ Q^T
            f32x16 s0 = {}, s1 = {};
            __builtin_amdgcn_s_setprio(1);
            #pragma unroll
            for (int kc = 0; kc < 4; ++kc) {
                bf16x8 kf0 = lds_frag(Kb_ + (l31) * 128 + ((2 * kc + hi) ^ r7) * 16);
                bf16x8 kf1 = lds_frag(Kb_ + (32 + l31) * 128 + ((2 * kc + hi) ^ r7) * 16);
                s0 = __builtin_amdgcn_mfma_f32_32x32x16_bf16(kf0, qf[kc], s0, 0, 0, 0);
                s1 = __builtin_amdgcn_mfma_f32_32x32x16_bf16(kf1, qf[kc], s1, 0, 0, 0);
            }
            __builtin_amdgcn_s_setprio(0);
            if (kt == bq) {   // diagonal tile: causal mask
                const int lim = qg - k0 - hi * 4;
                #pragma unroll
                for (int r2 = 0; r2 < 16; ++r2) {
                    const int ko = (r2 & 3) + 8 * (r2 >> 2);
                    s0[r2] = (ko > lim) ? -3.0e38f : s0[r2];
                    s1[r2] = (ko + 32 > lim) ? -3.0e38f : s1[r2];
                }
            }
            // tree max + cross-half exchange
            float a8[8];
            #pragma unroll
            for (int i = 0; i < 8; ++i)
                a8[i] = fmaxf(fmaxf(s0[2 * i], s0[2 * i + 1]), fmaxf(s1[2 * i], s1[2 * i + 1]));
            float tm = fmaxf(fmaxf(fmaxf(a8[0], a8[1]), fmaxf(a8[2], a8[3])),
                             fmaxf(fmaxf(a8[4], a8[5]), fmaxf(a8[6], a8[7])));
            tm = fmaxf(tm, __shfl_xor(tm, 32));
            // defer-max
            bool nofix = __all(tm <= mrow + THRraw);
            float scale = 1.f;
            if (!nofix) {
                float mnew = fmaxf(mrow, tm);
                scale = exp2f((mrow - mnew) * c2);
                mrow = mnew;
            }
            float mc = mrow * c2;
            #pragma unroll
            for (int r2 = 0; r2 < 16; ++r2) {
                s0[r2] = exp2f(__builtin_fmaf(s0[r2], c2, -mc));
                s1[r2] = exp2f(__builtin_fmaf(s1[r2], c2, -mc));
            }
            float c8[8];
            #pragma unroll
            for (int i = 0; i < 8; ++i)
                c8[i] = (s0[2 * i] + s0[2 * i + 1]) + (s1[2 * i] + s1[2 * i + 1]);
            float rsum = ((c8[0] + c8[1]) + (c8[2] + c8[3])) + ((c8[4] + c8[5]) + (c8[6] + c8[7]));
            rsum += __shfl_xor(rsum, 32);
            if (nofix) {
                lrow += rsum;
            } else {
                lrow = lrow * scale + rsum;
                #pragma unroll
                for (int r2 = 0; r2 < 16; ++r2) { acc0[r2] *= scale; acc1[r2] *= scale; }
            }
            // pack P to bf16 pairs
            u32 cg0[4][2], cg1[4][2];
            #pragma unroll
            for (int g = 0; g < 4; ++g) {
                #pragma unroll
                for (int w2 = 0; w2 < 2; ++w2) {
                    cg0[g][w2] = cvtpk_bf16(s0[4 * g + 2 * w2], s0[4 * g + 2 * w2 + 1]);
                    cg1[g][w2] = cvtpk_bf16(s1[4 * g + 2 * w2], s1[4 * g + 2 * w2 + 1]);
                }
            }
            // assemble P frags via shfl_xor(32): pa[ks] = P[q][16ks + 8hi + 0..7]
            bf16x8 pa[4];
            #pragma unroll
            for (int ks = 0; ks < 4; ++ks) {
                const int g0 = (2 * ks) & 3, g1 = g0 + 1;
                u32 a0, a1, b0, b1;
                if (ks < 2) { a0 = cg0[g0][0]; a1 = cg0[g0][1]; b0 = cg0[g1][0]; b1 = cg0[g1][1]; }
                else        { a0 = cg1[g0][0]; a1 = cg1[g0][1]; b0 = cg1[g1][0]; b1 = cg1[g1][1]; }
                u32 pa0 = (u32)__shfl_xor((int)a0, 32);
                u32 pa1 = (u32)__shfl_xor((int)a1, 32);
                u32 pb0 = (u32)__shfl_xor((int)b0, 32);
                u32 pb1 = (u32)__shfl_xor((int)b1, 32);
                u32x4 f;
                f.x = hi ? pb0 : a0;
                f.y = hi ? pb1 : a1;
                f.z = hi ? b0 : pa0;
                f.w = hi ? b1 : pa1;
                pa[ks] = __builtin_bit_cast(bf16x8, f);
            }
            // O^T += V^T @ P^T
            __builtin_amdgcn_s_setprio(1);
            #pragma unroll
            for (int ks = 0; ks < 4; ++ks) {
                bf16x8 vf0 = lds_frag(Vb_ + (l31) * 128 + ((2 * ks + hi) ^ r7) * 16);
                bf16x8 vf1 = lds_frag(Vb_ + (32 + l31) * 128 + ((2 * ks + hi) ^ r7) * 16);
                acc0 = __builtin_amdgcn_mfma_f32_32x32x16_bf16(vf0, pa[ks], acc0, 0, 0, 0);
                acc1 = __builtin_amdgcn_mfma_f32_32x32x16_bf16(vf1, pa[ks], acc1, 0, 0, 0);
            }
            __builtin_amdgcn_s_setprio(0);
        }
        __syncthreads();   // all reads done; safe to restage next round
    }
#undef STAGE2

    // write partials to LDS as bf16 (aliases staging region; all compute done)
    u16* partb = (u16*)lds;                      // [4][32][72] u16 = 18432 B
    float* mls = (float*)(lds + 18432);          // [4][2][32]  = 1024 B
    #pragma unroll
    for (int r2 = 0; r2 < 16; r2 += 2) {
        const int d0 = (r2 & 3) + 8 * (r2 >> 2) + 4 * hi;   // even; pair (r2, r2+1) -> d0, d0+1
        *reinterpret_cast<u32*>(&partb[(w * 32 + l31) * 72 + d0]) =
            cvtpk_bf16(acc0[r2], acc0[r2 + 1]);
        *reinterpret_cast<u32*>(&partb[(w * 32 + l31) * 72 + d0 + 32]) =
            cvtpk_bf16(acc1[r2], acc1[r2 + 1]);
    }
    if (hi == 0) {
        mls[(w * 2 + 0) * 32 + l31] = mrow;
        mls[(w * 2 + 1) * 32 + l31] = lrow;
    }
    __syncthreads();

    // combine 2 partials: thread -> q = tid>>2 (0..63), d-seg = (tid&3)*16
    {
        const int q = tid >> 2, ds0 = (tid & 3) * 16;
        const int s_ = q >> 5, qq = q & 31;
        const int wa_ = s_, wb_ = 2 + s_;
        float ma = mls[(wa_ * 2 + 0) * 32 + qq], la = mls[(wa_ * 2 + 1) * 32 + qq];
        float mb = mls[(wb_ * 2 + 0) * 32 + qq], lb = mls[(wb_ * 2 + 1) * 32 + qq];
        float mt = fmaxf(ma, mb);
        float wa = exp2f((ma - mt) * c2);
        float wb = exp2f((mb - mt) * c2);
        float lt = la * wa + lb * wb;
        float inv = 1.0f / lt;
        u16x8 pa0 = *reinterpret_cast<const u16x8*>(&partb[(wa_ * 32 + qq) * 72 + ds0]);
        u16x8 pa1 = *reinterpret_cast<const u16x8*>(&partb[(wa_ * 32 + qq) * 72 + ds0 + 8]);
        u16x8 pb0 = *reinterpret_cast<const u16x8*>(&partb[(wb_ * 32 + qq) * 72 + ds0]);
        u16x8 pb1 = *reinterpret_cast<const u16x8*>(&partb[(wb_ * 32 + qq) * 72 + ds0 + 8]);
        u16x8 ov0, ov1;
        #pragma unroll
        for (int i = 0; i < 8; ++i) {
            float v0 = bf2f(pa0[i]) * wa + bf2f(pb0[i]) * wb;
            float v1 = bf2f(pa1[i]) * wa + bf2f(pb1[i]) * wb;
            ov0[i] = f2bf(v0 * inv);
            ov1[i] = f2bf(v1 * inv);
        }
        u16* op = O + (size_t)(b * SS + q0 + q) * 1024 + head * 64 + ds0;
        *reinterpret_cast<u16x8*>(op) = ov0;
        *reinterpret_cast<u16x8*>(op + 8) = ov1;
    }
}

// ---------------- launch ----------------

extern "C" void kernel_launch(void* const* d_in, const int* in_sizes, int n_in,
                              void* d_out, int out_size, void* d_ws, size_t ws_size,
                              hipStream_t stream) {
    const float* x     = (const float*)d_in[0];
    const float* W_dq  = (const float*)d_in[1];
    const float* W_uq  = (const float*)d_in[2];
    const float* W_dkv = (const float*)d_in[3];
    const float* W_uk  = (const float*)d_in[4];
    const float* W_uv  = (const float*)d_in[5];
    const float* W_o   = (const float*)d_in[6];
    float* out = (float*)d_out;

    char* ws = (char*)d_ws;
    u16* c_qkv   = (u16*)(ws + (8u << 20));             // 4 MB   [4096][512]
    u16* Qb      = (u16*)(ws + (12u << 20));            // 8 MB   [4096][1024]
    u16* Kb      = (u16*)(ws + (20u << 20));            // 8 MB   [4096][1024] (K only)
    u16* Vt      = (u16*)(ws + (36u << 20));            // 8 MB   [2048][2048]
    u16* attno   = (u16*)(ws + (44u << 20));            // 8 MB   [4096][1024]
    u16* Wdqkv_t = (u16*)(ws + (52u << 20));            // 1 MB   [512][1024]
    u16* Wuq_t   = (u16*)(ws + (53u << 20));            // 0.5 MB [1024][256]
    u16* Wukv_t  = (u16*)(ws + (53u << 20) + (512u << 10)); // 1 MB [2048][256]
    u16* Wo_t    = (u16*)(ws + (55u << 20));            // 2 MB   [1024][1024]

    dim3 blk(256);
    // weight transposes only (x handled in gemm_dqkv)
    prep<<<dim3(32, 32, 6), blk, 0, stream>>>(W_dq, W_dkv, W_uq, W_uk, W_uv, W_o,
        Wdqkv_t, Wdqkv_t + 256 * 1024, Wuq_t, Wukv_t, Wukv_t + 1024 * 256, Wo_t);
    // c_qkv = x(f32) @ [W_dq | W_dkv]   BK=64, fused fp32->bf16 A staging
    gemm_dqkv<<<dim3(8, 64), blk, 0, stream>>>(x, Wdqkv_t, c_qkv);
    // Q | K | V(transposed) up-projection, K=256  (768 blocks)
    gemm_qkv<<<dim3(24, 32), blk, 0, stream>>>(c_qkv, Wuq_t, Wukv_t, Qb, Kb, Vt);
    // attention: 1024 blocks, pair-parity split, single-buffered staging, 5 blocks/CU
    attn_mfma6<<<dim3(1024), blk, 0, stream>>>(Qb, Kb, Vt, attno);
    // out = attno @ W_o   BK=64, BM=64/BN=128 -> 512 blocks, fp32 out
    gemm_out<<<dim3(8, 64), blk, 0, stream>>>(attno, Wo_t, out);
}